// Round 12
// baseline (671.924 us; speedup 1.0000x reference)
//
#include <hip/hip_runtime.h>

#define NG 64
#define REP 8          // aggpool replicas
#define GSC 512        // scatter grid blocks
#define NBK_MAX 1024   // max buckets (N <= 65536)

typedef __bf16 bf16x8 __attribute__((ext_vector_type(8)));
typedef float  f32x4  __attribute__((ext_vector_type(4)));

__device__ __forceinline__ ushort f2bf(float f) {
    unsigned int b = __float_as_uint(f);
    b += 0x7fffu + ((b >> 16) & 1u);   // RTNE
    return (ushort)(b >> 16);
}

// ---------------- pass A: per-block bucket counts (LDS int hist), 3 types ----------------
__global__ __launch_bounds__(256) void bucket_count3(
    const int* __restrict__ d0, int E0, int nbk0, int* __restrict__ c0,
    const int* __restrict__ d1, int E1, int nbk1, int* __restrict__ c1,
    const int* __restrict__ d2, int E2, int nbk2, int* __restrict__ c2)
{
    const int* dst; int E, nbk; int* cntA;
    if (blockIdx.y == 0) { dst = d0; E = E0; nbk = nbk0; cntA = c0; }
    else if (blockIdx.y == 1) { dst = d1; E = E1; nbk = nbk1; cntA = c1; }
    else { dst = d2; E = E2; nbk = nbk2; cntA = c2; }
    __shared__ int h[NBK_MAX];
    for (int i = threadIdx.x; i < nbk; i += 256) h[i] = 0;
    __syncthreads();
    int chunk = (E + GSC - 1) / GSC;
    int i0 = blockIdx.x * chunk, i1 = min(E, i0 + chunk);
    for (int i = i0 + threadIdx.x; i < i1; i += 256)
        atomicAdd(&h[dst[i] >> 6], 1);
    __syncthreads();
    for (int i = threadIdx.x; i < nbk; i += 256)
        cntA[(size_t)i * GSC + blockIdx.x] = h[i];
}

// ---------------- in-place scan over blocks per bucket, 3 types ----------------
__global__ __launch_bounds__(GSC) void scan_blocks3(
    int* __restrict__ c0, int nbk0, int* __restrict__ bt0,
    int* __restrict__ c1, int nbk1, int* __restrict__ bt1,
    int* __restrict__ c2, int nbk2, int* __restrict__ bt2)
{
    int* cntA; int nbk; int* btot;
    if (blockIdx.y == 0) { cntA = c0; nbk = nbk0; btot = bt0; }
    else if (blockIdx.y == 1) { cntA = c1; nbk = nbk1; btot = bt1; }
    else { cntA = c2; nbk = nbk2; btot = bt2; }
    int b = blockIdx.x;
    if (b >= nbk) return;
    int t = threadIdx.x, lane = t & 63, wv = t >> 6;   // 8 waves
    __shared__ int wsum[8];
    int v = cntA[(size_t)b * GSC + t];
    int x = v;
    #pragma unroll
    for (int off = 1; off < 64; off <<= 1) { int u = __shfl_up(x, off, 64); if (lane >= off) x += u; }
    if (lane == 63) wsum[wv] = x;
    __syncthreads();
    if (wv == 0 && lane < 8) {
        int w = wsum[lane];
        #pragma unroll
        for (int off = 1; off < 8; off <<= 1) { int u = __shfl_up(w, off, 64); if (lane >= off) w += u; }
        wsum[lane] = w;
    }
    __syncthreads();
    int incl = x + (wv > 0 ? wsum[wv - 1] : 0);
    cntA[(size_t)b * GSC + t] = incl - v;       // in-place exclusive base
    if (t == GSC - 1) btot[b] = incl;
}

// ---------------- exclusive scan of bucket totals -> bbase, 3 types ----------------
__global__ __launch_bounds__(1024) void scan_buckets3(
    const int* __restrict__ bt0, int nbk0, int* __restrict__ bb0,
    const int* __restrict__ bt1, int nbk1, int* __restrict__ bb1,
    const int* __restrict__ bt2, int nbk2, int* __restrict__ bb2)
{
    const int* btot; int nbk; int* bbase;
    if (blockIdx.x == 0) { btot = bt0; nbk = nbk0; bbase = bb0; }
    else if (blockIdx.x == 1) { btot = bt1; nbk = nbk1; bbase = bb1; }
    else { btot = bt2; nbk = nbk2; bbase = bb2; }
    int t = threadIdx.x, lane = t & 63, wv = t >> 6;
    __shared__ int wsum[16];
    int v = (t < nbk) ? btot[t] : 0;
    int x = v;
    #pragma unroll
    for (int off = 1; off < 64; off <<= 1) { int u = __shfl_up(x, off, 64); if (lane >= off) x += u; }
    if (lane == 63) wsum[wv] = x;
    __syncthreads();
    if (wv == 0 && lane < 16) {
        int w = wsum[lane];
        #pragma unroll
        for (int off = 1; off < 16; off <<= 1) { int u = __shfl_up(w, off, 64); if (lane >= off) w += u; }
        wsum[lane] = w;
    }
    __syncthreads();
    int incl = x + (wv > 0 ? wsum[wv - 1] : 0);
    if (t <= nbk) bbase[t] = incl - v;
}

// ---------------- pass B: scatter (src,dst) into bucket-grouped ebuf, 3 types ----------------
__global__ __launch_bounds__(256) void bucket_scatter3(
    const int* __restrict__ s0, const int* __restrict__ d0, int E0, int nbk0,
    const int* __restrict__ ba0, const int* __restrict__ bb0, int2* __restrict__ eb0,
    const int* __restrict__ s1, const int* __restrict__ d1, int E1, int nbk1,
    const int* __restrict__ ba1, const int* __restrict__ bb1, int2* __restrict__ eb1,
    const int* __restrict__ s2, const int* __restrict__ d2, int E2, int nbk2,
    const int* __restrict__ ba2, const int* __restrict__ bb2, int2* __restrict__ eb2)
{
    const int *src, *dst, *basesA, *bbase; int E, nbk; int2* ebuf;
    if (blockIdx.y == 0) { src = s0; dst = d0; E = E0; nbk = nbk0; basesA = ba0; bbase = bb0; ebuf = eb0; }
    else if (blockIdx.y == 1) { src = s1; dst = d1; E = E1; nbk = nbk1; basesA = ba1; bbase = bb1; ebuf = eb1; }
    else { src = s2; dst = d2; E = E2; nbk = nbk2; basesA = ba2; bbase = bb2; ebuf = eb2; }
    __shared__ int cur[NBK_MAX];
    for (int i = threadIdx.x; i < nbk; i += 256)
        cur[i] = bbase[i] + basesA[(size_t)i * GSC + blockIdx.x];
    __syncthreads();
    int chunk = (E + GSC - 1) / GSC;
    int i0 = blockIdx.x * chunk, i1 = min(E, i0 + chunk);
    for (int i = i0 + threadIdx.x; i < i1; i += 256) {
        int d = dst[i];
        int pos = atomicAdd(&cur[d >> 6], 1);
        ebuf[pos] = make_int2(src[i], d);
    }
}

// ---------------- per-bucket exact CSR from bucket-grouped edges, 3 types ----------------
__global__ __launch_bounds__(256) void csrify3(
    const int2* __restrict__ eb0, const int* __restrict__ bb0, int M0, int E0, int nbk0,
    int* __restrict__ rp0, int* __restrict__ cs0,
    const int2* __restrict__ eb1, const int* __restrict__ bb1, int M1, int E1, int nbk1,
    int* __restrict__ rp1, int* __restrict__ cs1,
    const int2* __restrict__ eb2, const int* __restrict__ bb2, int M2, int E2, int nbk2,
    int* __restrict__ rp2, int* __restrict__ cs2)
{
    const int2* ebuf; const int* bbase; int M, E, nbk; int *rp, *csr;
    if (blockIdx.y == 0) { ebuf = eb0; bbase = bb0; M = M0; E = E0; nbk = nbk0; rp = rp0; csr = cs0; }
    else if (blockIdx.y == 1) { ebuf = eb1; bbase = bb1; M = M1; E = E1; nbk = nbk1; rp = rp1; csr = cs1; }
    else { ebuf = eb2; bbase = bb2; M = M2; E = E2; nbk = nbk2; rp = rp2; csr = cs2; }
    if ((int)blockIdx.x >= nbk) return;
    __shared__ int hist[64], cur[64];
    int t = threadIdx.x;
    if (t < 64) hist[t] = 0;
    __syncthreads();
    int e0 = bbase[blockIdx.x], e1 = bbase[blockIdx.x + 1];
    for (int e = e0 + t; e < e1; e += 256)
        atomicAdd(&hist[ebuf[e].y & 63], 1);
    __syncthreads();
    if (t < 64) {
        int x = hist[t];
        #pragma unroll
        for (int off = 1; off < 64; off <<= 1) { int u = __shfl_up(x, off, 64); if (t >= off) x += u; }
        int ex = x - hist[t];
        cur[t] = ex;
        int row = (blockIdx.x << 6) + t;
        if (row < M) rp[row] = e0 + ex;
    }
    if (blockIdx.x == 0 && t == 0) rp[M] = E;
    __syncthreads();
    for (int e = e0 + t; e < e1; e += 256) {
        int2 p = ebuf[e];
        int pos = atomicAdd(&cur[p.y & 63], 1);
        csr[e0 + pos] = p.x;
    }
}

// ---------------- elementwise add (bias sums) ----------------
__global__ void add2_kernel(const float* __restrict__ a, const float* __restrict__ b,
                            float* __restrict__ o, int n) {
    int i = blockIdx.x * blockDim.x + threadIdx.x;
    if (i < n) o[i] = a[i] + b[i];
}

// ---------------- f32 -> bf16 conversion ----------------
__global__ void cvt_kernel(const float* __restrict__ x, ushort* __restrict__ o, int n4) {
    int i = blockIdx.x * blockDim.x + threadIdx.x;
    if (i >= n4) return;
    float4 v = ((const float4*)x)[i];
    ushort4 r;
    r.x = f2bf(v.x); r.y = f2bf(v.y); r.z = f2bf(v.z); r.w = f2bf(v.w);
    ((ushort4*)o)[i] = r;
}

// ---------------- weight prep: Wt[n][k] = bf16(Wa[k][n] (+Wb[k][n])) ----------------
__global__ void wprep_kernel(
    const float* __restrict__ Wa0, const float* __restrict__ Wb0, ushort* __restrict__ Wt0,
    const float* __restrict__ Wa1, ushort* __restrict__ Wt1,
    const float* __restrict__ Wa2, ushort* __restrict__ Wt2,
    const float* __restrict__ Wa3, ushort* __restrict__ Wt3,
    const float* __restrict__ Wa4, ushort* __restrict__ Wt4)
{
    const float* Wa; const float* Wb = nullptr; ushort* Wt;
    switch (blockIdx.x) {
        case 0: Wa = Wa0; Wb = Wb0; Wt = Wt0; break;
        case 1: Wa = Wa1; Wt = Wt1; break;
        case 2: Wa = Wa2; Wt = Wt2; break;
        case 3: Wa = Wa3; Wt = Wt3; break;
        default: Wa = Wa4; Wt = Wt4; break;
    }
    for (int idx = threadIdx.x; idx < 128 * 128; idx += 256) {
        int n = idx >> 7, k = idx & 127;
        float v = Wa[k * 128 + n];
        if (Wb) v += Wb[k * 128 + n];
        Wt[idx] = f2bf(v);
    }
}

// ---------------- graph boundaries via binary search (batch is sorted) ----------------
__global__ void bounds_kernel(const int* __restrict__ bu, int nu,
                              const int* __restrict__ bd, int nd,
                              int* __restrict__ bndu, int* __restrict__ bndd)
{
    const int* b = blockIdx.x == 0 ? bu : bd;
    int        n = blockIdx.x == 0 ? nu : nd;
    int*       o = blockIdx.x == 0 ? bndu : bndd;
    int g = threadIdx.x;
    if (g > NG) return;
    int lo = 0, hi = n;
    while (lo < hi) { int m = (lo + hi) >> 1; if (b[m] < g) lo = m + 1; else hi = m; }
    o[g] = lo;
}

// 16-deep gather accumulate: issues all loads before consuming
#define GATHER16(J)                                                                  \
    {                                                                                \
        unsigned int v[16];                                                          \
        _Pragma("unroll")                                                            \
        for (int k = 0; k < 16; ++k)                                                 \
            v[k] = *(const unsigned int*)&xb[(size_t)csr[(J) + k] * 128 + lane * 2]; \
        _Pragma("unroll")                                                            \
        for (int k = 0; k < 16; ++k) {                                               \
            sx += __uint_as_float(v[k] << 16);                                       \
            sy += __uint_as_float(v[k] & 0xffff0000u);                               \
        }                                                                            \
    }

// ---------------- CSR mean aggregation (3 types in one launch, 16-deep) ----------------
__global__ __launch_bounds__(256) void agg3_kernel(
    const ushort* __restrict__ x0, const int* __restrict__ rpa, const int* __restrict__ csa, int Ma, ushort* __restrict__ ma,
    const ushort* __restrict__ x1, const int* __restrict__ rpb, const int* __restrict__ csb, int Mb, ushort* __restrict__ mb,
    const ushort* __restrict__ x2, const int* __restrict__ rpc, const int* __restrict__ csc, int Mc, ushort* __restrict__ mc)
{
    const ushort* xb; const int *rp, *csr; int M; ushort* mean;
    if (blockIdx.y == 0) { xb = x0; rp = rpa; csr = csa; M = Ma; mean = ma; }
    else if (blockIdx.y == 1) { xb = x1; rp = rpb; csr = csb; M = Mb; mean = mb; }
    else { xb = x2; rp = rpc; csr = csc; M = Mc; mean = mc; }
    int wave = threadIdx.x >> 6, lane = threadIdx.x & 63;
    int row = blockIdx.x * 4 + wave;
    if (row >= M) return;
    int s0 = rp[row], s1 = rp[row + 1];
    float sx = 0.f, sy = 0.f;
    int j = s0;
    for (; j + 16 <= s1; j += 16) GATHER16(j)
    for (; j < s1; ++j) {
        unsigned int v = *(const unsigned int*)&xb[(size_t)csr[j] * 128 + lane * 2];
        sx += __uint_as_float(v << 16);
        sy += __uint_as_float(v & 0xffff0000u);
    }
    int deg = s1 - s0;
    float sc = 1.f / (float)(deg > 1 ? deg : 1);
    unsigned int pk = (unsigned int)f2bf(sx * sc) | ((unsigned int)f2bf(sy * sc) << 16);
    *(unsigned int*)&mean[(size_t)row * 128 + lane * 2] = pk;
}

// ---------------- MFMA multi-term GEMM: C = relu(sum A_t @ W_t + bias) -> bf16 ----------------
template<int NA>
__global__ __launch_bounds__(256) void gemm_mfma(
    const ushort* __restrict__ A0, const ushort* __restrict__ A1, const ushort* __restrict__ A2,
    const ushort* __restrict__ Wt0, const ushort* __restrict__ Wt1, const ushort* __restrict__ Wt2,
    int M, const float* __restrict__ bias, ushort* __restrict__ C)
{
    int wave = threadIdx.x >> 6, lane = threadIdx.x & 63;
    int row0 = blockIdx.x * 64 + wave * 16;
    int r  = lane & 15;
    int kg = lane >> 4;
    f32x4 acc[8];
    #pragma unroll
    for (int nt = 0; nt < 8; ++nt) acc[nt] = (f32x4){0.f, 0.f, 0.f, 0.f};

    int arow = row0 + r;
    int arow_c = arow < M ? arow : 0;
    #pragma unroll
    for (int term = 0; term < NA; ++term) {
        const ushort* A  = (term == 0) ? A0  : (term == 1 ? A1  : A2);
        const ushort* Wt = (term == 0) ? Wt0 : (term == 1 ? Wt1 : Wt2);
        #pragma unroll
        for (int kk = 0; kk < 4; ++kk) {
            bf16x8 a = *(const bf16x8*)&A[(size_t)arow_c * 128 + kk * 32 + kg * 8];
            #pragma unroll
            for (int nt = 0; nt < 8; ++nt) {
                bf16x8 b = *(const bf16x8*)&Wt[(size_t)(nt * 16 + r) * 128 + kk * 32 + kg * 8];
                acc[nt] = __builtin_amdgcn_mfma_f32_16x16x32_bf16(a, b, acc[nt], 0, 0, 0);
            }
        }
    }

    #pragma unroll
    for (int nt = 0; nt < 8; ++nt) {
        int col = nt * 16 + r;
        float bv = bias[col];
        #pragma unroll
        for (int j = 0; j < 4; ++j) {
            int orow = row0 + kg * 4 + j;
            if (orow < M) {
                float v = fmaxf(acc[nt][j] + bv, 0.f);
                C[(size_t)orow * 128 + col] = f2bf(v);
            }
        }
    }
}

// ---------------- fused layer-2 agg + per-graph pool (4 rows/wave, 16-deep, replicated, 3 types) ----------------
__global__ __launch_bounds__(256) void aggpool3_kernel(
    const ushort* __restrict__ x0, const int* __restrict__ rpa, const int* __restrict__ csa,
    const int* __restrict__ ba, int Ma, float* __restrict__ pa,
    const ushort* __restrict__ x1, const int* __restrict__ rpb, const int* __restrict__ csb,
    const int* __restrict__ bb, int Mb, float* __restrict__ pb,
    const ushort* __restrict__ x2, const int* __restrict__ rpc, const int* __restrict__ csc,
    const int* __restrict__ bc, int Mc, float* __restrict__ pc)
{
    const ushort* xb; const int *rp, *csr, *batch; int M; float* pool;
    if (blockIdx.y == 0) { xb = x0; rp = rpa; csr = csa; batch = ba; M = Ma; pool = pa; }
    else if (blockIdx.y == 1) { xb = x1; rp = rpb; csr = csb; batch = bb; M = Mb; pool = pb; }
    else { xb = x2; rp = rpc; csr = csc; batch = bc; M = Mc; pool = pc; }
    int wave = threadIdx.x >> 6, lane = threadIdx.x & 63;
    int r0 = (blockIdx.x * 4 + wave) * 4;
    if (r0 >= M) return;
    int r1 = min(M, r0 + 4);
    float* p = pool + (size_t)(blockIdx.x & (REP - 1)) * NG * 128;
    float ax = 0.f, ay = 0.f;
    int curg = batch[r0];
    for (int row = r0; row < r1; ++row) {
        int g = batch[row];
        if (g != curg) {
            atomicAdd(&p[curg * 128 + lane * 2],     ax);
            atomicAdd(&p[curg * 128 + lane * 2 + 1], ay);
            ax = 0.f; ay = 0.f; curg = g;
        }
        int s0 = rp[row], s1 = rp[row + 1];
        float sx = 0.f, sy = 0.f;
        int j = s0;
        for (; j + 16 <= s1; j += 16) GATHER16(j)
        for (; j < s1; ++j) {
            unsigned int v = *(const unsigned int*)&xb[(size_t)csr[j] * 128 + lane * 2];
            sx += __uint_as_float(v << 16);
            sy += __uint_as_float(v & 0xffff0000u);
        }
        int deg = s1 - s0;
        float sc = 1.f / (float)(deg > 1 ? deg : 1);
        ax += sx * sc; ay += sy * sc;
    }
    atomicAdd(&p[curg * 128 + lane * 2],     ax);
    atomicAdd(&p[curg * 128 + lane * 2 + 1], ay);
}

// ---------------- 2-way per-graph row-sum pool (u1b, d1b) ----------------
__global__ __launch_bounds__(256) void pool2_kernel(
    const ushort* __restrict__ u1b, const ushort* __restrict__ d1b,
    const int* __restrict__ bndu, const int* __restrict__ bndd,
    float* __restrict__ pu1, float* __restrict__ pd1)
{
    const ushort* xb; const int* bnd; float* pool;
    if (blockIdx.y == 0) { xb = u1b; bnd = bndu; pool = pu1; }
    else { xb = d1b; bnd = bndd; pool = pd1; }
    int g = blockIdx.x;
    int lo = bnd[g], hi = bnd[g + 1];
    int c2 = threadIdx.x & 63, half = threadIdx.x >> 6;
    float sx = 0.f, sy = 0.f;
    for (int r = lo + half; r < hi; r += 4) {
        unsigned int v = *(const unsigned int*)&xb[(size_t)r * 128 + c2 * 2];
        sx += __uint_as_float(v << 16);
        sy += __uint_as_float(v & 0xffff0000u);
    }
    __shared__ float ls[256 * 2];
    ls[threadIdx.x * 2]     = sx;
    ls[threadIdx.x * 2 + 1] = sy;
    __syncthreads();
    if (half == 0) {
        float ox = ls[c2 * 2] + ls[(64 + c2) * 2] + ls[(128 + c2) * 2] + ls[(192 + c2) * 2];
        float oy = ls[c2 * 2 + 1] + ls[(64 + c2) * 2 + 1] + ls[(128 + c2) * 2 + 1] + ls[(192 + c2) * 2 + 1];
        pool[g * 128 + c2 * 2]     = ox;
        pool[g * 128 + c2 * 2 + 1] = oy;
    }
}

// ---------------- final: layer-2 matmuls at graph level + MLP + log_softmax ----------------
__global__ __launch_bounds__(128) void final_kernel(
    const float* __restrict__ pmdu, const float* __restrict__ pmuu, const float* __restrict__ pmud,
    const float* __restrict__ pu1,  const float* __restrict__ pd1,
    const int* __restrict__ bndu, const int* __restrict__ bndd,
    const float* __restrict__ Wl2_du, const float* __restrict__ bl2_du, const float* __restrict__ Wr2_du,
    const float* __restrict__ Wl2_uu, const float* __restrict__ bl2_uu, const float* __restrict__ Wr2_uu,
    const float* __restrict__ Wl2_ud, const float* __restrict__ bl2_ud, const float* __restrict__ Wr2_ud,
    const float* __restrict__ W1, const float* __restrict__ b1,
    const float* __restrict__ W2, const float* __restrict__ b2,
    float* __restrict__ out)
{
    int g = blockIdx.x, t = threadIdx.x;
    __shared__ float smdu[128], smuu[128], smud[128], su1[128], sd1[128];
    __shared__ float xrow[256], h[128], lg[2];
    float vdu = 0.f, vuu = 0.f, vud = 0.f;
    #pragma unroll
    for (int r = 0; r < REP; ++r) {
        vdu += pmdu[(size_t)r * NG * 128 + g * 128 + t];
        vuu += pmuu[(size_t)r * NG * 128 + g * 128 + t];
        vud += pmud[(size_t)r * NG * 128 + g * 128 + t];
    }
    smdu[t] = vdu;
    smuu[t] = vuu;
    smud[t] = vud;
    su1[t]  = pu1[g * 128 + t];
    sd1[t]  = pd1[g * 128 + t];
    __syncthreads();
    float ncu = (float)(bndu[g + 1] - bndu[g]);
    float ncd = (float)(bndd[g + 1] - bndd[g]);
    float cu = ncu > 1.f ? ncu : 1.f, cd = ncd > 1.f ? ncd : 1.f;
    float accu = ncu * (bl2_du[t] + bl2_uu[t]);
    float accd = ncd * bl2_ud[t];
    for (int k = 0; k < 128; ++k) {
        accu += smdu[k] * Wl2_du[k * 128 + t]
              + smuu[k] * Wl2_uu[k * 128 + t]
              + su1[k]  * (Wr2_du[k * 128 + t] + Wr2_uu[k * 128 + t]);
        accd += smud[k] * Wl2_ud[k * 128 + t]
              + sd1[k]  * Wr2_ud[k * 128 + t];
    }
    xrow[t]       = accu / cu;
    xrow[128 + t] = accd / cd;
    __syncthreads();
    float hh = b1[t];
    for (int k = 0; k < 256; ++k) hh += xrow[k] * W1[k * 128 + t];
    h[t] = fmaxf(hh, 0.f);
    __syncthreads();
    if (t < 2) {
        float l = b2[t];
        for (int k = 0; k < 128; ++k) l += h[k] * W2[k * 2 + t];
        lg[t] = l;
    }
    __syncthreads();
    if (t == 0) {
        float m = fmaxf(lg[0], lg[1]);
        float lse = m + logf(expf(lg[0] - m) + expf(lg[1] - m));
        out[g * 2 + 0] = lg[0] - lse;
        out[g * 2 + 1] = lg[1] - lse;
    }
}

extern "C" void kernel_launch(void* const* d_in, const int* in_sizes, int n_in,
                              void* d_out, int out_size, void* d_ws, size_t ws_size,
                              hipStream_t stream)
{
    const float* x_user = (const float*)d_in[0];
    const float* x_drug = (const float*)d_in[1];
    const int* ei_ud = (const int*)d_in[2];
    const int* ei_du = (const int*)d_in[3];
    const int* ei_uu = (const int*)d_in[4];
    const int* batch_u = (const int*)d_in[5];
    const int* batch_d = (const int*)d_in[6];
    const float* Wl1_ud = (const float*)d_in[7];  const float* bl1_ud = (const float*)d_in[8];  const float* Wr1_ud = (const float*)d_in[9];
    const float* Wl1_du = (const float*)d_in[10]; const float* bl1_du = (const float*)d_in[11]; const float* Wr1_du = (const float*)d_in[12];
    const float* Wl1_uu = (const float*)d_in[13]; const float* bl1_uu = (const float*)d_in[14]; const float* Wr1_uu = (const float*)d_in[15];
    const float* Wl2_ud = (const float*)d_in[16]; const float* bl2_ud = (const float*)d_in[17]; const float* Wr2_ud = (const float*)d_in[18];
    const float* Wl2_du = (const float*)d_in[19]; const float* bl2_du = (const float*)d_in[20]; const float* Wr2_du = (const float*)d_in[21];
    const float* Wl2_uu = (const float*)d_in[22]; const float* bl2_uu = (const float*)d_in[23]; const float* Wr2_uu = (const float*)d_in[24];
    const float* W1 = (const float*)d_in[25]; const float* b1 = (const float*)d_in[26];
    const float* W2 = (const float*)d_in[27]; const float* b2 = (const float*)d_in[28];
    (void)n_in; (void)out_size; (void)ws_size;

    const int Nu = in_sizes[0] / 128;
    const int Nd = in_sizes[1] / 128;
    const int E_ud = in_sizes[2] / 2;
    const int E_du = in_sizes[3] / 2;
    const int E_uu = in_sizes[4] / 2;
    const int nbk_u = (Nu + 63) >> 6;
    const int nbk_d = (Nd + 63) >> 6;
    const int nbk_max = nbk_u > nbk_d ? nbk_u : nbk_d;
    const int Nmax = Nu > Nd ? Nu : Nd;

    char* ws = (char*)d_ws;
    size_t off = 0;
    auto alloc = [&](size_t bytes) -> void* {
        void* p = ws + off;
        off = (off + bytes + 255) & ~(size_t)255;
        return p;
    };
    int2* ebuf_ud = (int2*)alloc((size_t)E_ud * 8);
    int2* ebuf_du = (int2*)alloc((size_t)E_du * 8);
    int2* ebuf_uu = (int2*)alloc((size_t)E_uu * 8);
    int* cntA_ud = (int*)alloc((size_t)NBK_MAX * GSC * 4);
    int* cntA_du = (int*)alloc((size_t)NBK_MAX * GSC * 4);
    int* cntA_uu = (int*)alloc((size_t)NBK_MAX * GSC * 4);
    int* btot_ud = (int*)alloc((size_t)NBK_MAX * 4);
    int* btot_du = (int*)alloc((size_t)NBK_MAX * 4);
    int* btot_uu = (int*)alloc((size_t)NBK_MAX * 4);
    int* bbase_ud = (int*)alloc((size_t)(NBK_MAX + 1) * 4);
    int* bbase_du = (int*)alloc((size_t)(NBK_MAX + 1) * 4);
    int* bbase_uu = (int*)alloc((size_t)(NBK_MAX + 1) * 4);
    int* csr_ud = (int*)alloc((size_t)E_ud * 4);
    int* csr_du = (int*)alloc((size_t)E_du * 4);
    int* csr_uu = (int*)alloc((size_t)E_uu * 4);
    int* rp_ud = (int*)alloc((size_t)(Nd + 1) * 4);
    int* rp_du = (int*)alloc((size_t)(Nu + 1) * 4);
    int* rp_uu = (int*)alloc((size_t)(Nu + 1) * 4);
    ushort* xb_u = (ushort*)alloc((size_t)Nu * 128 * 2);
    ushort* xb_d = (ushort*)alloc((size_t)Nd * 128 * 2);
    // layer-1 mean buffers overlay the ebufs (dead after csrify)
    ushort* mean_du = (ushort*)ebuf_du;   // [Nu,128] bf16
    ushort* mean_uu = (ushort*)ebuf_uu;   // [Nu,128]
    ushort* mean_ud = (ushort*)ebuf_ud;   // [Nd,128]
    ushort* u1b = (ushort*)alloc((size_t)Nu * 128 * 2);
    ushort* d1b = (ushort*)alloc((size_t)Nd * 128 * 2);
    float* pmdu = (float*)alloc((size_t)REP * NG * 128 * 4);
    float* pmuu = (float*)alloc((size_t)REP * NG * 128 * 4);
    float* pmud = (float*)alloc((size_t)REP * NG * 128 * 4);
    char* zero2_beg = (char*)pmdu;
    char* zero2_end = ws + off;
    float* pu1  = (float*)alloc(NG * 128 * 4);
    float* pd1  = (float*)alloc(NG * 128 * 4);
    int* bnd_u = (int*)alloc((NG + 1) * 4);
    int* bnd_d = (int*)alloc((NG + 1) * 4);
    ushort* Wt_ru  = (ushort*)alloc(128 * 128 * 2);
    ushort* Wt_ldu = (ushort*)alloc(128 * 128 * 2);
    ushort* Wt_luu = (ushort*)alloc(128 * 128 * 2);
    ushort* Wt_rud = (ushort*)alloc(128 * 128 * 2);
    ushort* Wt_lud = (ushort*)alloc(128 * 128 * 2);
    float* b1s_u  = (float*)alloc(128 * 4);

    const int* dst_ud = ei_ud + E_ud;
    const int* dst_du = ei_du + E_du;
    const int* dst_uu = ei_uu + E_uu;

    // ---- CSR build via LDS bucket sort (zero device atomics), 3 types per launch ----
    bucket_count3<<<dim3(GSC, 3), 256, 0, stream>>>(
        dst_ud, E_ud, nbk_d, cntA_ud,
        dst_du, E_du, nbk_u, cntA_du,
        dst_uu, E_uu, nbk_u, cntA_uu);
    scan_blocks3<<<dim3(nbk_max, 3), GSC, 0, stream>>>(
        cntA_ud, nbk_d, btot_ud,
        cntA_du, nbk_u, btot_du,
        cntA_uu, nbk_u, btot_uu);
    scan_buckets3<<<3, 1024, 0, stream>>>(
        btot_ud, nbk_d, bbase_ud,
        btot_du, nbk_u, bbase_du,
        btot_uu, nbk_u, bbase_uu);
    bucket_scatter3<<<dim3(GSC, 3), 256, 0, stream>>>(
        ei_ud, dst_ud, E_ud, nbk_d, cntA_ud, bbase_ud, ebuf_ud,
        ei_du, dst_du, E_du, nbk_u, cntA_du, bbase_du, ebuf_du,
        ei_uu, dst_uu, E_uu, nbk_u, cntA_uu, bbase_uu, ebuf_uu);
    csrify3<<<dim3(nbk_max, 3), 256, 0, stream>>>(
        ebuf_ud, bbase_ud, Nd, E_ud, nbk_d, rp_ud, csr_ud,
        ebuf_du, bbase_du, Nu, E_du, nbk_u, rp_du, csr_du,
        ebuf_uu, bbase_uu, Nu, E_uu, nbk_u, rp_uu, csr_uu);

    // ---- graph boundaries, bf16 inputs, weight prep, pm memset ----
    bounds_kernel<<<2, NG + 1, 0, stream>>>(batch_u, Nu, batch_d, Nd, bnd_u, bnd_d);
    cvt_kernel<<<(Nu * 32 + 255) / 256, 256, 0, stream>>>(x_user, xb_u, Nu * 32);
    cvt_kernel<<<(Nd * 32 + 255) / 256, 256, 0, stream>>>(x_drug, xb_d, Nd * 32);
    wprep_kernel<<<5, 256, 0, stream>>>(Wr1_du, Wr1_uu, Wt_ru,
                                        Wl1_du, Wt_ldu, Wl1_uu, Wt_luu,
                                        Wr1_ud, Wt_rud, Wl1_ud, Wt_lud);
    add2_kernel<<<1, 128, 0, stream>>>(bl1_du, bl1_uu, b1s_u, 128);
    hipMemsetAsync(zero2_beg, 0, (size_t)(zero2_end - zero2_beg), stream);

    // ---- layer-1 aggregation (3 types, one launch; means overlay dead ebufs) ----
    agg3_kernel<<<dim3((Nmax + 3) / 4, 3), 256, 0, stream>>>(
        xb_d, rp_du, csr_du, Nu, mean_du,
        xb_u, rp_uu, csr_uu, Nu, mean_uu,
        xb_u, rp_ud, csr_ud, Nd, mean_ud);

    // ---- layer-1 MFMA GEMMs -> bf16 ----
    gemm_mfma<3><<<(Nu + 63) / 64, 256, 0, stream>>>(xb_u, mean_du, mean_uu,
                                                     Wt_ru, Wt_ldu, Wt_luu, Nu, b1s_u, u1b);
    gemm_mfma<2><<<(Nd + 63) / 64, 256, 0, stream>>>(xb_d, mean_ud, nullptr,
                                                     Wt_rud, Wt_lud, nullptr, Nd, bl1_ud, d1b);

    // ---- layer 2: fused CSR-mean + per-graph pool (4 rows/wave, 16-deep, one launch) ----
    aggpool3_kernel<<<dim3((Nmax + 15) / 16, 3), 256, 0, stream>>>(
        d1b, rp_du, csr_du, batch_u, Nu, pmdu,
        u1b, rp_uu, csr_uu, batch_u, Nu, pmuu,
        u1b, rp_ud, csr_ud, batch_d, Nd, pmud);

    // ---- root-term pools (direct store) ----
    pool2_kernel<<<dim3(NG, 2), 256, 0, stream>>>(u1b, d1b, bnd_u, bnd_d, pu1, pd1);

    // ---- graph-level layer-2 matmuls + MLP + log_softmax ----
    final_kernel<<<NG, 128, 0, stream>>>(pmdu, pmuu, pmud, pu1, pd1, bnd_u, bnd_d,
                                         Wl2_du, bl2_du, Wr2_du,
                                         Wl2_uu, bl2_uu, Wr2_uu,
                                         Wl2_ud, bl2_ud, Wr2_ud,
                                         W1, b1, W2, b2, (float*)d_out);
}

// Round 13
// 654.736 us; speedup vs baseline: 1.0263x; 1.0263x over previous
//
#include <hip/hip_runtime.h>

#define NG 64
#define REP 8          // aggpool replicas
#define GSC 512        // scatter grid blocks
#define NBK_MAX 1024   // max buckets (N <= 65536)

typedef __bf16 bf16x8 __attribute__((ext_vector_type(8)));
typedef float  f32x4  __attribute__((ext_vector_type(4)));

__device__ __forceinline__ ushort f2bf(float f) {
    unsigned int b = __float_as_uint(f);
    b += 0x7fffu + ((b >> 16) & 1u);   // RTNE
    return (ushort)(b >> 16);
}

// ---- fp8 e4m3fn helpers (no subnormal encode; decode exact via exponent-shift trick) ----
__device__ __forceinline__ float fp8_to_f32(unsigned v8) {
    unsigned b = ((v8 & 0x80u) << 24) | ((v8 & 0x7fu) << 20);
    return __uint_as_float(b) * 1.329227995784916e36f;   // 2^120
}
__device__ __forceinline__ unsigned char f2fp8(float f) {
    float a = fabsf(f);
    unsigned s = (__float_as_uint(f) >> 24) & 0x80u;
    if (a < 0.015625f) return (unsigned char)0;          // flush sub-min-normal
    if (a > 440.f) return (unsigned char)(s | 0x7eu);    // clamp to 448
    unsigned b = __float_as_uint(a * 7.52316384526264e-37f);  // 2^-120
    b += 0x7ffffu + ((b >> 20) & 1u);                    // RNE to 3 mantissa bits
    return (unsigned char)(s | ((b >> 20) & 0x7fu));
}

// ---------------- pass A: per-block bucket counts (LDS int hist), 3 types ----------------
__global__ __launch_bounds__(256) void bucket_count3(
    const int* __restrict__ d0, int E0, int nbk0, int* __restrict__ c0,
    const int* __restrict__ d1, int E1, int nbk1, int* __restrict__ c1,
    const int* __restrict__ d2, int E2, int nbk2, int* __restrict__ c2)
{
    const int* dst; int E, nbk; int* cntA;
    if (blockIdx.y == 0) { dst = d0; E = E0; nbk = nbk0; cntA = c0; }
    else if (blockIdx.y == 1) { dst = d1; E = E1; nbk = nbk1; cntA = c1; }
    else { dst = d2; E = E2; nbk = nbk2; cntA = c2; }
    __shared__ int h[NBK_MAX];
    for (int i = threadIdx.x; i < nbk; i += 256) h[i] = 0;
    __syncthreads();
    int chunk = (E + GSC - 1) / GSC;
    int i0 = blockIdx.x * chunk, i1 = min(E, i0 + chunk);
    for (int i = i0 + threadIdx.x; i < i1; i += 256)
        atomicAdd(&h[dst[i] >> 6], 1);
    __syncthreads();
    for (int i = threadIdx.x; i < nbk; i += 256)
        cntA[(size_t)i * GSC + blockIdx.x] = h[i];
}

// ---------------- in-place scan over blocks per bucket, 3 types ----------------
__global__ __launch_bounds__(GSC) void scan_blocks3(
    int* __restrict__ c0, int nbk0, int* __restrict__ bt0,
    int* __restrict__ c1, int nbk1, int* __restrict__ bt1,
    int* __restrict__ c2, int nbk2, int* __restrict__ bt2)
{
    int* cntA; int nbk; int* btot;
    if (blockIdx.y == 0) { cntA = c0; nbk = nbk0; btot = bt0; }
    else if (blockIdx.y == 1) { cntA = c1; nbk = nbk1; btot = bt1; }
    else { cntA = c2; nbk = nbk2; btot = bt2; }
    int b = blockIdx.x;
    if (b >= nbk) return;
    int t = threadIdx.x, lane = t & 63, wv = t >> 6;   // 8 waves
    __shared__ int wsum[8];
    int v = cntA[(size_t)b * GSC + t];
    int x = v;
    #pragma unroll
    for (int off = 1; off < 64; off <<= 1) { int u = __shfl_up(x, off, 64); if (lane >= off) x += u; }
    if (lane == 63) wsum[wv] = x;
    __syncthreads();
    if (wv == 0 && lane < 8) {
        int w = wsum[lane];
        #pragma unroll
        for (int off = 1; off < 8; off <<= 1) { int u = __shfl_up(w, off, 64); if (lane >= off) w += u; }
        wsum[lane] = w;
    }
    __syncthreads();
    int incl = x + (wv > 0 ? wsum[wv - 1] : 0);
    cntA[(size_t)b * GSC + t] = incl - v;       // in-place exclusive base
    if (t == GSC - 1) btot[b] = incl;
}

// ---------------- exclusive scan of bucket totals -> bbase, 3 types ----------------
__global__ __launch_bounds__(1024) void scan_buckets3(
    const int* __restrict__ bt0, int nbk0, int* __restrict__ bb0,
    const int* __restrict__ bt1, int nbk1, int* __restrict__ bb1,
    const int* __restrict__ bt2, int nbk2, int* __restrict__ bb2)
{
    const int* btot; int nbk; int* bbase;
    if (blockIdx.x == 0) { btot = bt0; nbk = nbk0; bbase = bb0; }
    else if (blockIdx.x == 1) { btot = bt1; nbk = nbk1; bbase = bb1; }
    else { btot = bt2; nbk = nbk2; bbase = bb2; }
    int t = threadIdx.x, lane = t & 63, wv = t >> 6;
    __shared__ int wsum[16];
    int v = (t < nbk) ? btot[t] : 0;
    int x = v;
    #pragma unroll
    for (int off = 1; off < 64; off <<= 1) { int u = __shfl_up(x, off, 64); if (lane >= off) x += u; }
    if (lane == 63) wsum[wv] = x;
    __syncthreads();
    if (wv == 0 && lane < 16) {
        int w = wsum[lane];
        #pragma unroll
        for (int off = 1; off < 16; off <<= 1) { int u = __shfl_up(w, off, 64); if (lane >= off) w += u; }
        wsum[lane] = w;
    }
    __syncthreads();
    int incl = x + (wv > 0 ? wsum[wv - 1] : 0);
    if (t <= nbk) bbase[t] = incl - v;
}

// ---------------- pass B: scatter (src,dst) into bucket-grouped ebuf, 3 types ----------------
__global__ __launch_bounds__(256) void bucket_scatter3(
    const int* __restrict__ s0, const int* __restrict__ d0, int E0, int nbk0,
    const int* __restrict__ ba0, const int* __restrict__ bb0, int2* __restrict__ eb0,
    const int* __restrict__ s1, const int* __restrict__ d1, int E1, int nbk1,
    const int* __restrict__ ba1, const int* __restrict__ bb1, int2* __restrict__ eb1,
    const int* __restrict__ s2, const int* __restrict__ d2, int E2, int nbk2,
    const int* __restrict__ ba2, const int* __restrict__ bb2, int2* __restrict__ eb2)
{
    const int *src, *dst, *basesA, *bbase; int E, nbk; int2* ebuf;
    if (blockIdx.y == 0) { src = s0; dst = d0; E = E0; nbk = nbk0; basesA = ba0; bbase = bb0; ebuf = eb0; }
    else if (blockIdx.y == 1) { src = s1; dst = d1; E = E1; nbk = nbk1; basesA = ba1; bbase = bb1; ebuf = eb1; }
    else { src = s2; dst = d2; E = E2; nbk = nbk2; basesA = ba2; bbase = bb2; ebuf = eb2; }
    __shared__ int cur[NBK_MAX];
    for (int i = threadIdx.x; i < nbk; i += 256)
        cur[i] = bbase[i] + basesA[(size_t)i * GSC + blockIdx.x];
    __syncthreads();
    int chunk = (E + GSC - 1) / GSC;
    int i0 = blockIdx.x * chunk, i1 = min(E, i0 + chunk);
    for (int i = i0 + threadIdx.x; i < i1; i += 256) {
        int d = dst[i];
        int pos = atomicAdd(&cur[d >> 6], 1);
        ebuf[pos] = make_int2(src[i], d);
    }
}

// ---------------- per-bucket exact CSR from bucket-grouped edges, 3 types ----------------
__global__ __launch_bounds__(256) void csrify3(
    const int2* __restrict__ eb0, const int* __restrict__ bb0, int M0, int E0, int nbk0,
    int* __restrict__ rp0, int* __restrict__ cs0,
    const int2* __restrict__ eb1, const int* __restrict__ bb1, int M1, int E1, int nbk1,
    int* __restrict__ rp1, int* __restrict__ cs1,
    const int2* __restrict__ eb2, const int* __restrict__ bb2, int M2, int E2, int nbk2,
    int* __restrict__ rp2, int* __restrict__ cs2)
{
    const int2* ebuf; const int* bbase; int M, E, nbk; int *rp, *csr;
    if (blockIdx.y == 0) { ebuf = eb0; bbase = bb0; M = M0; E = E0; nbk = nbk0; rp = rp0; csr = cs0; }
    else if (blockIdx.y == 1) { ebuf = eb1; bbase = bb1; M = M1; E = E1; nbk = nbk1; rp = rp1; csr = cs1; }
    else { ebuf = eb2; bbase = bb2; M = M2; E = E2; nbk = nbk2; rp = rp2; csr = cs2; }
    if ((int)blockIdx.x >= nbk) return;
    __shared__ int hist[64], cur[64];
    int t = threadIdx.x;
    if (t < 64) hist[t] = 0;
    __syncthreads();
    int e0 = bbase[blockIdx.x], e1 = bbase[blockIdx.x + 1];
    for (int e = e0 + t; e < e1; e += 256)
        atomicAdd(&hist[ebuf[e].y & 63], 1);
    __syncthreads();
    if (t < 64) {
        int x = hist[t];
        #pragma unroll
        for (int off = 1; off < 64; off <<= 1) { int u = __shfl_up(x, off, 64); if (t >= off) x += u; }
        int ex = x - hist[t];
        cur[t] = ex;
        int row = (blockIdx.x << 6) + t;
        if (row < M) rp[row] = e0 + ex;
    }
    if (blockIdx.x == 0 && t == 0) rp[M] = E;
    __syncthreads();
    for (int e = e0 + t; e < e1; e += 256) {
        int2 p = ebuf[e];
        int pos = atomicAdd(&cur[p.y & 63], 1);
        csr[e0 + pos] = p.x;
    }
}

// ---------------- elementwise add (bias sums) ----------------
__global__ void add2_kernel(const float* __restrict__ a, const float* __restrict__ b,
                            float* __restrict__ o, int n) {
    int i = blockIdx.x * blockDim.x + threadIdx.x;
    if (i < n) o[i] = a[i] + b[i];
}

// ---------------- f32 -> bf16 + fp8 dual conversion ----------------
__global__ void cvt_dual_kernel(const float* __restrict__ x, ushort* __restrict__ ob,
                                unsigned char* __restrict__ o8, int n4) {
    int i = blockIdx.x * blockDim.x + threadIdx.x;
    if (i >= n4) return;
    float4 v = ((const float4*)x)[i];
    ushort4 rb;
    rb.x = f2bf(v.x); rb.y = f2bf(v.y); rb.z = f2bf(v.z); rb.w = f2bf(v.w);
    ((ushort4*)ob)[i] = rb;
    uchar4 r8;
    r8.x = f2fp8(v.x); r8.y = f2fp8(v.y); r8.z = f2fp8(v.z); r8.w = f2fp8(v.w);
    ((uchar4*)o8)[i] = r8;
}

// ---------------- weight prep: Wt[n][k] = bf16(Wa[k][n] (+Wb[k][n])) ----------------
__global__ void wprep_kernel(
    const float* __restrict__ Wa0, const float* __restrict__ Wb0, ushort* __restrict__ Wt0,
    const float* __restrict__ Wa1, ushort* __restrict__ Wt1,
    const float* __restrict__ Wa2, ushort* __restrict__ Wt2,
    const float* __restrict__ Wa3, ushort* __restrict__ Wt3,
    const float* __restrict__ Wa4, ushort* __restrict__ Wt4)
{
    const float* Wa; const float* Wb = nullptr; ushort* Wt;
    switch (blockIdx.x) {
        case 0: Wa = Wa0; Wb = Wb0; Wt = Wt0; break;
        case 1: Wa = Wa1; Wt = Wt1; break;
        case 2: Wa = Wa2; Wt = Wt2; break;
        case 3: Wa = Wa3; Wt = Wt3; break;
        default: Wa = Wa4; Wt = Wt4; break;
    }
    for (int idx = threadIdx.x; idx < 128 * 128; idx += 256) {
        int n = idx >> 7, k = idx & 127;
        float v = Wa[k * 128 + n];
        if (Wb) v += Wb[k * 128 + n];
        Wt[idx] = f2bf(v);
    }
}

// ---------------- graph boundaries via binary search (batch is sorted) ----------------
__global__ void bounds_kernel(const int* __restrict__ bu, int nu,
                              const int* __restrict__ bd, int nd,
                              int* __restrict__ bndu, int* __restrict__ bndd)
{
    const int* b = blockIdx.x == 0 ? bu : bd;
    int        n = blockIdx.x == 0 ? nu : nd;
    int*       o = blockIdx.x == 0 ? bndu : bndd;
    int g = threadIdx.x;
    if (g > NG) return;
    int lo = 0, hi = n;
    while (lo < hi) { int m = (lo + hi) >> 1; if (b[m] < g) lo = m + 1; else hi = m; }
    o[g] = lo;
}

// 8-deep fp8 gather accumulate (rows are 128 fp8 = 128B; lane covers 2 cols)
#define GATHER8(J)                                                                   \
    {                                                                                \
        ushort w0 = *(const ushort*)&xf8[(size_t)csr[(J) + 0] * 128 + lane * 2];     \
        ushort w1 = *(const ushort*)&xf8[(size_t)csr[(J) + 1] * 128 + lane * 2];     \
        ushort w2 = *(const ushort*)&xf8[(size_t)csr[(J) + 2] * 128 + lane * 2];     \
        ushort w3 = *(const ushort*)&xf8[(size_t)csr[(J) + 3] * 128 + lane * 2];     \
        ushort w4 = *(const ushort*)&xf8[(size_t)csr[(J) + 4] * 128 + lane * 2];     \
        ushort w5 = *(const ushort*)&xf8[(size_t)csr[(J) + 5] * 128 + lane * 2];     \
        ushort w6 = *(const ushort*)&xf8[(size_t)csr[(J) + 6] * 128 + lane * 2];     \
        ushort w7 = *(const ushort*)&xf8[(size_t)csr[(J) + 7] * 128 + lane * 2];     \
        sx += fp8_to_f32(w0 & 0xffu) + fp8_to_f32(w1 & 0xffu)                        \
            + fp8_to_f32(w2 & 0xffu) + fp8_to_f32(w3 & 0xffu)                        \
            + fp8_to_f32(w4 & 0xffu) + fp8_to_f32(w5 & 0xffu)                        \
            + fp8_to_f32(w6 & 0xffu) + fp8_to_f32(w7 & 0xffu);                       \
        sy += fp8_to_f32(w0 >> 8) + fp8_to_f32(w1 >> 8)                              \
            + fp8_to_f32(w2 >> 8) + fp8_to_f32(w3 >> 8)                              \
            + fp8_to_f32(w4 >> 8) + fp8_to_f32(w5 >> 8)                              \
            + fp8_to_f32(w6 >> 8) + fp8_to_f32(w7 >> 8);                             \
    }

// ---------------- CSR mean aggregation (3 types, fp8 gather -> bf16 means) ----------------
__global__ __launch_bounds__(256) void agg3_kernel(
    const unsigned char* __restrict__ x0, const int* __restrict__ rpa, const int* __restrict__ csa, int Ma, ushort* __restrict__ ma,
    const unsigned char* __restrict__ x1, const int* __restrict__ rpb, const int* __restrict__ csb, int Mb, ushort* __restrict__ mb,
    const unsigned char* __restrict__ x2, const int* __restrict__ rpc, const int* __restrict__ csc, int Mc, ushort* __restrict__ mc)
{
    const unsigned char* xf8; const int *rp, *csr; int M; ushort* mean;
    if (blockIdx.y == 0) { xf8 = x0; rp = rpa; csr = csa; M = Ma; mean = ma; }
    else if (blockIdx.y == 1) { xf8 = x1; rp = rpb; csr = csb; M = Mb; mean = mb; }
    else { xf8 = x2; rp = rpc; csr = csc; M = Mc; mean = mc; }
    int wave = threadIdx.x >> 6, lane = threadIdx.x & 63;
    int row = blockIdx.x * 4 + wave;
    if (row >= M) return;
    int s0 = rp[row], s1 = rp[row + 1];
    float sx = 0.f, sy = 0.f;
    int j = s0;
    for (; j + 8 <= s1; j += 8) GATHER8(j)
    for (; j < s1; ++j) {
        ushort w = *(const ushort*)&xf8[(size_t)csr[j] * 128 + lane * 2];
        sx += fp8_to_f32(w & 0xffu);
        sy += fp8_to_f32(w >> 8);
    }
    int deg = s1 - s0;
    float sc = 1.f / (float)(deg > 1 ? deg : 1);
    unsigned int pk = (unsigned int)f2bf(sx * sc) | ((unsigned int)f2bf(sy * sc) << 16);
    *(unsigned int*)&mean[(size_t)row * 128 + lane * 2] = pk;
}

// ---------------- MFMA multi-term GEMM: C = relu(sum A_t @ W_t + bias) -> fp8 ----------------
template<int NA>
__global__ __launch_bounds__(256) void gemm_mfma(
    const ushort* __restrict__ A0, const ushort* __restrict__ A1, const ushort* __restrict__ A2,
    const ushort* __restrict__ Wt0, const ushort* __restrict__ Wt1, const ushort* __restrict__ Wt2,
    int M, const float* __restrict__ bias, unsigned char* __restrict__ C)
{
    int wave = threadIdx.x >> 6, lane = threadIdx.x & 63;
    int row0 = blockIdx.x * 64 + wave * 16;
    int r  = lane & 15;
    int kg = lane >> 4;
    f32x4 acc[8];
    #pragma unroll
    for (int nt = 0; nt < 8; ++nt) acc[nt] = (f32x4){0.f, 0.f, 0.f, 0.f};

    int arow = row0 + r;
    int arow_c = arow < M ? arow : 0;
    #pragma unroll
    for (int term = 0; term < NA; ++term) {
        const ushort* A  = (term == 0) ? A0  : (term == 1 ? A1  : A2);
        const ushort* Wt = (term == 0) ? Wt0 : (term == 1 ? Wt1 : Wt2);
        #pragma unroll
        for (int kk = 0; kk < 4; ++kk) {
            bf16x8 a = *(const bf16x8*)&A[(size_t)arow_c * 128 + kk * 32 + kg * 8];
            #pragma unroll
            for (int nt = 0; nt < 8; ++nt) {
                bf16x8 b = *(const bf16x8*)&Wt[(size_t)(nt * 16 + r) * 128 + kk * 32 + kg * 8];
                acc[nt] = __builtin_amdgcn_mfma_f32_16x16x32_bf16(a, b, acc[nt], 0, 0, 0);
            }
        }
    }

    #pragma unroll
    for (int nt = 0; nt < 8; ++nt) {
        int col = nt * 16 + r;
        float bv = bias[col];
        #pragma unroll
        for (int j = 0; j < 4; ++j) {
            int orow = row0 + kg * 4 + j;
            if (orow < M) {
                float v = fmaxf(acc[nt][j] + bv, 0.f);
                C[(size_t)orow * 128 + col] = f2fp8(v);
            }
        }
    }
}

// ---------------- fused layer-2 agg + per-graph pool (4 rows/wave, fp8, replicated, 3 types) ----------------
__global__ __launch_bounds__(256) void aggpool3_kernel(
    const unsigned char* __restrict__ x0, const int* __restrict__ rpa, const int* __restrict__ csa,
    const int* __restrict__ ba, int Ma, float* __restrict__ pa,
    const unsigned char* __restrict__ x1, const int* __restrict__ rpb, const int* __restrict__ csb,
    const int* __restrict__ bb, int Mb, float* __restrict__ pb,
    const unsigned char* __restrict__ x2, const int* __restrict__ rpc, const int* __restrict__ csc,
    const int* __restrict__ bc, int Mc, float* __restrict__ pc)
{
    const unsigned char* xf8; const int *rp, *csr, *batch; int M; float* pool;
    if (blockIdx.y == 0) { xf8 = x0; rp = rpa; csr = csa; batch = ba; M = Ma; pool = pa; }
    else if (blockIdx.y == 1) { xf8 = x1; rp = rpb; csr = csb; batch = bb; M = Mb; pool = pb; }
    else { xf8 = x2; rp = rpc; csr = csc; batch = bc; M = Mc; pool = pc; }
    int wave = threadIdx.x >> 6, lane = threadIdx.x & 63;
    int r0 = (blockIdx.x * 4 + wave) * 4;
    if (r0 >= M) return;
    int r1 = min(M, r0 + 4);
    float* p = pool + (size_t)(blockIdx.x & (REP - 1)) * NG * 128;
    float ax = 0.f, ay = 0.f;
    int curg = batch[r0];
    for (int row = r0; row < r1; ++row) {
        int g = batch[row];
        if (g != curg) {
            atomicAdd(&p[curg * 128 + lane * 2],     ax);
            atomicAdd(&p[curg * 128 + lane * 2 + 1], ay);
            ax = 0.f; ay = 0.f; curg = g;
        }
        int s0 = rp[row], s1 = rp[row + 1];
        float sx = 0.f, sy = 0.f;
        int j = s0;
        for (; j + 8 <= s1; j += 8) GATHER8(j)
        for (; j < s1; ++j) {
            ushort w = *(const ushort*)&xf8[(size_t)csr[j] * 128 + lane * 2];
            sx += fp8_to_f32(w & 0xffu);
            sy += fp8_to_f32(w >> 8);
        }
        int deg = s1 - s0;
        float sc = 1.f / (float)(deg > 1 ? deg : 1);
        ax += sx * sc; ay += sy * sc;
    }
    atomicAdd(&p[curg * 128 + lane * 2],     ax);
    atomicAdd(&p[curg * 128 + lane * 2 + 1], ay);
}

// ---------------- 2-way per-graph row-sum pool over fp8 rows (batch sorted) ----------------
__global__ __launch_bounds__(256) void pool2_kernel(
    const unsigned char* __restrict__ u1f, const unsigned char* __restrict__ d1f,
    const int* __restrict__ bndu, const int* __restrict__ bndd,
    float* __restrict__ pu1, float* __restrict__ pd1)
{
    const unsigned char* xf8; const int* bnd; float* pool;
    if (blockIdx.y == 0) { xf8 = u1f; bnd = bndu; pool = pu1; }
    else { xf8 = d1f; bnd = bndd; pool = pd1; }
    int g = blockIdx.x;
    int lo = bnd[g], hi = bnd[g + 1];
    int c2 = threadIdx.x & 63, half = threadIdx.x >> 6;
    float sx = 0.f, sy = 0.f;
    for (int r = lo + half; r < hi; r += 4) {
        ushort w = *(const ushort*)&xf8[(size_t)r * 128 + c2 * 2];
        sx += fp8_to_f32(w & 0xffu);
        sy += fp8_to_f32(w >> 8);
    }
    __shared__ float ls[256 * 2];
    ls[threadIdx.x * 2]     = sx;
    ls[threadIdx.x * 2 + 1] = sy;
    __syncthreads();
    if (half == 0) {
        float ox = ls[c2 * 2] + ls[(64 + c2) * 2] + ls[(128 + c2) * 2] + ls[(192 + c2) * 2];
        float oy = ls[c2 * 2 + 1] + ls[(64 + c2) * 2 + 1] + ls[(128 + c2) * 2 + 1] + ls[(192 + c2) * 2 + 1];
        pool[g * 128 + c2 * 2]     = ox;
        pool[g * 128 + c2 * 2 + 1] = oy;
    }
}

// ---------------- final: layer-2 matmuls at graph level + MLP + log_softmax ----------------
__global__ __launch_bounds__(128) void final_kernel(
    const float* __restrict__ pmdu, const float* __restrict__ pmuu, const float* __restrict__ pmud,
    const float* __restrict__ pu1,  const float* __restrict__ pd1,
    const int* __restrict__ bndu, const int* __restrict__ bndd,
    const float* __restrict__ Wl2_du, const float* __restrict__ bl2_du, const float* __restrict__ Wr2_du,
    const float* __restrict__ Wl2_uu, const float* __restrict__ bl2_uu, const float* __restrict__ Wr2_uu,
    const float* __restrict__ Wl2_ud, const float* __restrict__ bl2_ud, const float* __restrict__ Wr2_ud,
    const float* __restrict__ W1, const float* __restrict__ b1,
    const float* __restrict__ W2, const float* __restrict__ b2,
    float* __restrict__ out)
{
    int g = blockIdx.x, t = threadIdx.x;
    __shared__ float smdu[128], smuu[128], smud[128], su1[128], sd1[128];
    __shared__ float xrow[256], h[128], lg[2];
    float vdu = 0.f, vuu = 0.f, vud = 0.f;
    #pragma unroll
    for (int r = 0; r < REP; ++r) {
        vdu += pmdu[(size_t)r * NG * 128 + g * 128 + t];
        vuu += pmuu[(size_t)r * NG * 128 + g * 128 + t];
        vud += pmud[(size_t)r * NG * 128 + g * 128 + t];
    }
    smdu[t] = vdu;
    smuu[t] = vuu;
    smud[t] = vud;
    su1[t]  = pu1[g * 128 + t];
    sd1[t]  = pd1[g * 128 + t];
    __syncthreads();
    float ncu = (float)(bndu[g + 1] - bndu[g]);
    float ncd = (float)(bndd[g + 1] - bndd[g]);
    float cu = ncu > 1.f ? ncu : 1.f, cd = ncd > 1.f ? ncd : 1.f;
    float accu = ncu * (bl2_du[t] + bl2_uu[t]);
    float accd = ncd * bl2_ud[t];
    for (int k = 0; k < 128; ++k) {
        accu += smdu[k] * Wl2_du[k * 128 + t]
              + smuu[k] * Wl2_uu[k * 128 + t]
              + su1[k]  * (Wr2_du[k * 128 + t] + Wr2_uu[k * 128 + t]);
        accd += smud[k] * Wl2_ud[k * 128 + t]
              + sd1[k]  * Wr2_ud[k * 128 + t];
    }
    xrow[t]       = accu / cu;
    xrow[128 + t] = accd / cd;
    __syncthreads();
    float hh = b1[t];
    for (int k = 0; k < 256; ++k) hh += xrow[k] * W1[k * 128 + t];
    h[t] = fmaxf(hh, 0.f);
    __syncthreads();
    if (t < 2) {
        float l = b2[t];
        for (int k = 0; k < 128; ++k) l += h[k] * W2[k * 2 + t];
        lg[t] = l;
    }
    __syncthreads();
    if (t == 0) {
        float m = fmaxf(lg[0], lg[1]);
        float lse = m + logf(expf(lg[0] - m) + expf(lg[1] - m));
        out[g * 2 + 0] = lg[0] - lse;
        out[g * 2 + 1] = lg[1] - lse;
    }
}

extern "C" void kernel_launch(void* const* d_in, const int* in_sizes, int n_in,
                              void* d_out, int out_size, void* d_ws, size_t ws_size,
                              hipStream_t stream)
{
    const float* x_user = (const float*)d_in[0];
    const float* x_drug = (const float*)d_in[1];
    const int* ei_ud = (const int*)d_in[2];
    const int* ei_du = (const int*)d_in[3];
    const int* ei_uu = (const int*)d_in[4];
    const int* batch_u = (const int*)d_in[5];
    const int* batch_d = (const int*)d_in[6];
    const float* Wl1_ud = (const float*)d_in[7];  const float* bl1_ud = (const float*)d_in[8];  const float* Wr1_ud = (const float*)d_in[9];
    const float* Wl1_du = (const float*)d_in[10]; const float* bl1_du = (const float*)d_in[11]; const float* Wr1_du = (const float*)d_in[12];
    const float* Wl1_uu = (const float*)d_in[13]; const float* bl1_uu = (const float*)d_in[14]; const float* Wr1_uu = (const float*)d_in[15];
    const float* Wl2_ud = (const float*)d_in[16]; const float* bl2_ud = (const float*)d_in[17]; const float* Wr2_ud = (const float*)d_in[18];
    const float* Wl2_du = (const float*)d_in[19]; const float* bl2_du = (const float*)d_in[20]; const float* Wr2_du = (const float*)d_in[21];
    const float* Wl2_uu = (const float*)d_in[22]; const float* bl2_uu = (const float*)d_in[23]; const float* Wr2_uu = (const float*)d_in[24];
    const float* W1 = (const float*)d_in[25]; const float* b1 = (const float*)d_in[26];
    const float* W2 = (const float*)d_in[27]; const float* b2 = (const float*)d_in[28];
    (void)n_in; (void)out_size; (void)ws_size;

    const int Nu = in_sizes[0] / 128;
    const int Nd = in_sizes[1] / 128;
    const int E_ud = in_sizes[2] / 2;
    const int E_du = in_sizes[3] / 2;
    const int E_uu = in_sizes[4] / 2;
    const int nbk_u = (Nu + 63) >> 6;
    const int nbk_d = (Nd + 63) >> 6;
    const int nbk_max = nbk_u > nbk_d ? nbk_u : nbk_d;
    const int Nmax = Nu > Nd ? Nu : Nd;

    char* ws = (char*)d_ws;
    size_t off = 0;
    auto alloc = [&](size_t bytes) -> void* {
        void* p = ws + off;
        off = (off + bytes + 255) & ~(size_t)255;
        return p;
    };
    int2* ebuf_ud = (int2*)alloc((size_t)E_ud * 8);
    int2* ebuf_du = (int2*)alloc((size_t)E_du * 8);
    int2* ebuf_uu = (int2*)alloc((size_t)E_uu * 8);
    int* cntA_ud = (int*)alloc((size_t)NBK_MAX * GSC * 4);
    int* cntA_du = (int*)alloc((size_t)NBK_MAX * GSC * 4);
    int* cntA_uu = (int*)alloc((size_t)NBK_MAX * GSC * 4);
    int* btot_ud = (int*)alloc((size_t)NBK_MAX * 4);
    int* btot_du = (int*)alloc((size_t)NBK_MAX * 4);
    int* btot_uu = (int*)alloc((size_t)NBK_MAX * 4);
    int* bbase_ud = (int*)alloc((size_t)(NBK_MAX + 1) * 4);
    int* bbase_du = (int*)alloc((size_t)(NBK_MAX + 1) * 4);
    int* bbase_uu = (int*)alloc((size_t)(NBK_MAX + 1) * 4);
    int* csr_ud = (int*)alloc((size_t)E_ud * 4);
    int* csr_du = (int*)alloc((size_t)E_du * 4);
    int* csr_uu = (int*)alloc((size_t)E_uu * 4);
    int* rp_ud = (int*)alloc((size_t)(Nd + 1) * 4);
    int* rp_du = (int*)alloc((size_t)(Nu + 1) * 4);
    int* rp_uu = (int*)alloc((size_t)(Nu + 1) * 4);
    ushort* xb_u = (ushort*)alloc((size_t)Nu * 128 * 2);    // bf16 (MFMA A-operand)
    ushort* xb_d = (ushort*)alloc((size_t)Nd * 128 * 2);
    unsigned char* xf8_u = (unsigned char*)alloc((size_t)Nu * 128);   // fp8 gather tables
    unsigned char* xf8_d = (unsigned char*)alloc((size_t)Nd * 128);
    // layer-1 mean buffers overlay the ebufs (dead after csrify)
    ushort* mean_du = (ushort*)ebuf_du;   // [Nu,128] bf16
    ushort* mean_uu = (ushort*)ebuf_uu;   // [Nu,128]
    ushort* mean_ud = (ushort*)ebuf_ud;   // [Nd,128]
    unsigned char* u1f = (unsigned char*)alloc((size_t)Nu * 128);   // layer-1 out, fp8
    unsigned char* d1f = (unsigned char*)alloc((size_t)Nd * 128);
    float* pmdu = (float*)alloc((size_t)REP * NG * 128 * 4);
    float* pmuu = (float*)alloc((size_t)REP * NG * 128 * 4);
    float* pmud = (float*)alloc((size_t)REP * NG * 128 * 4);
    char* zero2_beg = (char*)pmdu;
    char* zero2_end = ws + off;
    float* pu1  = (float*)alloc(NG * 128 * 4);
    float* pd1  = (float*)alloc(NG * 128 * 4);
    int* bnd_u = (int*)alloc((NG + 1) * 4);
    int* bnd_d = (int*)alloc((NG + 1) * 4);
    ushort* Wt_ru  = (ushort*)alloc(128 * 128 * 2);
    ushort* Wt_ldu = (ushort*)alloc(128 * 128 * 2);
    ushort* Wt_luu = (ushort*)alloc(128 * 128 * 2);
    ushort* Wt_rud = (ushort*)alloc(128 * 128 * 2);
    ushort* Wt_lud = (ushort*)alloc(128 * 128 * 2);
    float* b1s_u  = (float*)alloc(128 * 4);

    const int* dst_ud = ei_ud + E_ud;
    const int* dst_du = ei_du + E_du;
    const int* dst_uu = ei_uu + E_uu;

    // ---- CSR build via LDS bucket sort (zero device atomics), 3 types per launch ----
    bucket_count3<<<dim3(GSC, 3), 256, 0, stream>>>(
        dst_ud, E_ud, nbk_d, cntA_ud,
        dst_du, E_du, nbk_u, cntA_du,
        dst_uu, E_uu, nbk_u, cntA_uu);
    scan_blocks3<<<dim3(nbk_max, 3), GSC, 0, stream>>>(
        cntA_ud, nbk_d, btot_ud,
        cntA_du, nbk_u, btot_du,
        cntA_uu, nbk_u, btot_uu);
    scan_buckets3<<<3, 1024, 0, stream>>>(
        btot_ud, nbk_d, bbase_ud,
        btot_du, nbk_u, bbase_du,
        btot_uu, nbk_u, bbase_uu);
    bucket_scatter3<<<dim3(GSC, 3), 256, 0, stream>>>(
        ei_ud, dst_ud, E_ud, nbk_d, cntA_ud, bbase_ud, ebuf_ud,
        ei_du, dst_du, E_du, nbk_u, cntA_du, bbase_du, ebuf_du,
        ei_uu, dst_uu, E_uu, nbk_u, cntA_uu, bbase_uu, ebuf_uu);
    csrify3<<<dim3(nbk_max, 3), 256, 0, stream>>>(
        ebuf_ud, bbase_ud, Nd, E_ud, nbk_d, rp_ud, csr_ud,
        ebuf_du, bbase_du, Nu, E_du, nbk_u, rp_du, csr_du,
        ebuf_uu, bbase_uu, Nu, E_uu, nbk_u, rp_uu, csr_uu);

    // ---- graph boundaries, bf16+fp8 inputs, weight prep, pm memset ----
    bounds_kernel<<<2, NG + 1, 0, stream>>>(batch_u, Nu, batch_d, Nd, bnd_u, bnd_d);
    cvt_dual_kernel<<<(Nu * 32 + 255) / 256, 256, 0, stream>>>(x_user, xb_u, xf8_u, Nu * 32);
    cvt_dual_kernel<<<(Nd * 32 + 255) / 256, 256, 0, stream>>>(x_drug, xb_d, xf8_d, Nd * 32);
    wprep_kernel<<<5, 256, 0, stream>>>(Wr1_du, Wr1_uu, Wt_ru,
                                        Wl1_du, Wt_ldu, Wl1_uu, Wt_luu,
                                        Wr1_ud, Wt_rud, Wl1_ud, Wt_lud);
    add2_kernel<<<1, 128, 0, stream>>>(bl1_du, bl1_uu, b1s_u, 128);
    hipMemsetAsync(zero2_beg, 0, (size_t)(zero2_end - zero2_beg), stream);

    // ---- layer-1 aggregation (fp8 gather, 3 types, one launch; means overlay dead ebufs) ----
    agg3_kernel<<<dim3((Nmax + 3) / 4, 3), 256, 0, stream>>>(
        xf8_d, rp_du, csr_du, Nu, mean_du,
        xf8_u, rp_uu, csr_uu, Nu, mean_uu,
        xf8_u, rp_ud, csr_ud, Nd, mean_ud);

    // ---- layer-1 MFMA GEMMs -> fp8 ----
    gemm_mfma<3><<<(Nu + 63) / 64, 256, 0, stream>>>(xb_u, mean_du, mean_uu,
                                                     Wt_ru, Wt_ldu, Wt_luu, Nu, b1s_u, u1f);
    gemm_mfma<2><<<(Nd + 63) / 64, 256, 0, stream>>>(xb_d, mean_ud, nullptr,
                                                     Wt_rud, Wt_lud, nullptr, Nd, bl1_ud, d1f);

    // ---- layer 2: fused CSR-mean + per-graph pool (fp8 gather, replicated, one launch) ----
    aggpool3_kernel<<<dim3((Nmax + 15) / 16, 3), 256, 0, stream>>>(
        d1f, rp_du, csr_du, batch_u, Nu, pmdu,
        u1f, rp_uu, csr_uu, batch_u, Nu, pmuu,
        u1f, rp_ud, csr_ud, batch_d, Nd, pmud);

    // ---- root-term pools (direct store, fp8 stream) ----
    pool2_kernel<<<dim3(NG, 2), 256, 0, stream>>>(u1f, d1f, bnd_u, bnd_d, pu1, pd1);

    // ---- graph-level layer-2 matmuls + MLP + log_softmax ----
    final_kernel<<<NG, 128, 0, stream>>>(pmdu, pmuu, pmud, pu1, pd1, bnd_u, bnd_d,
                                         Wl2_du, bl2_du, Wr2_du,
                                         Wl2_uu, bl2_uu, Wr2_uu,
                                         Wl2_ud, bl2_ud, Wr2_ud,
                                         W1, b1, W2, b2, (float*)d_out);
}

// Round 14
// 577.427 us; speedup vs baseline: 1.1637x; 1.1339x over previous
//
#include <hip/hip_runtime.h>

#define NG 64
#define REP 8          // aggpool replicas
#define GSC 512        // scatter grid blocks
#define NBK_MAX 1024   // max buckets (N <= 65536)

typedef __bf16 bf16x8 __attribute__((ext_vector_type(8)));
typedef float  f32x4  __attribute__((ext_vector_type(4)));
typedef float  f32x2  __attribute__((ext_vector_type(2)));

__device__ __forceinline__ ushort f2bf(float f) {
    unsigned int b = __float_as_uint(f);
    b += 0x7fffu + ((b >> 16) & 1u);   // RTNE
    return (ushort)(b >> 16);
}

// ---- fp8 e4m3 (OCP) via gfx950 HW converters ----
__device__ __forceinline__ f32x2 fp8pair(unsigned w) {           // decode bytes 0,1
    return __builtin_amdgcn_cvt_pk_f32_fp8((int)w, false);
}
__device__ __forceinline__ unsigned fp8enc2(float a, float b) {  // encode pair -> bytes 0,1
    return (unsigned)__builtin_amdgcn_cvt_pk_fp8_f32(a, b, 0, false) & 0xffffu;
}
__device__ __forceinline__ unsigned char fp8enc1(float a) {
    return (unsigned char)(__builtin_amdgcn_cvt_pk_fp8_f32(a, 0.f, 0, false) & 0xff);
}

// ---------------- pass A: per-block bucket counts (LDS int hist), 3 types ----------------
__global__ __launch_bounds__(256) void bucket_count3(
    const int* __restrict__ d0, int E0, int nbk0, int* __restrict__ c0,
    const int* __restrict__ d1, int E1, int nbk1, int* __restrict__ c1,
    const int* __restrict__ d2, int E2, int nbk2, int* __restrict__ c2)
{
    const int* dst; int E, nbk; int* cntA;
    if (blockIdx.y == 0) { dst = d0; E = E0; nbk = nbk0; cntA = c0; }
    else if (blockIdx.y == 1) { dst = d1; E = E1; nbk = nbk1; cntA = c1; }
    else { dst = d2; E = E2; nbk = nbk2; cntA = c2; }
    __shared__ int h[NBK_MAX];
    for (int i = threadIdx.x; i < nbk; i += 256) h[i] = 0;
    __syncthreads();
    int chunk = (E + GSC - 1) / GSC;
    int i0 = blockIdx.x * chunk, i1 = min(E, i0 + chunk);
    for (int i = i0 + threadIdx.x; i < i1; i += 256)
        atomicAdd(&h[dst[i] >> 6], 1);
    __syncthreads();
    for (int i = threadIdx.x; i < nbk; i += 256)
        cntA[(size_t)i * GSC + blockIdx.x] = h[i];
}

// ---------------- in-place scan over blocks per bucket, 3 types ----------------
__global__ __launch_bounds__(GSC) void scan_blocks3(
    int* __restrict__ c0, int nbk0, int* __restrict__ bt0,
    int* __restrict__ c1, int nbk1, int* __restrict__ bt1,
    int* __restrict__ c2, int nbk2, int* __restrict__ bt2)
{
    int* cntA; int nbk; int* btot;
    if (blockIdx.y == 0) { cntA = c0; nbk = nbk0; btot = bt0; }
    else if (blockIdx.y == 1) { cntA = c1; nbk = nbk1; btot = bt1; }
    else { cntA = c2; nbk = nbk2; btot = bt2; }
    int b = blockIdx.x;
    if (b >= nbk) return;
    int t = threadIdx.x, lane = t & 63, wv = t >> 6;   // 8 waves
    __shared__ int wsum[8];
    int v = cntA[(size_t)b * GSC + t];
    int x = v;
    #pragma unroll
    for (int off = 1; off < 64; off <<= 1) { int u = __shfl_up(x, off, 64); if (lane >= off) x += u; }
    if (lane == 63) wsum[wv] = x;
    __syncthreads();
    if (wv == 0 && lane < 8) {
        int w = wsum[lane];
        #pragma unroll
        for (int off = 1; off < 8; off <<= 1) { int u = __shfl_up(w, off, 64); if (lane >= off) w += u; }
        wsum[lane] = w;
    }
    __syncthreads();
    int incl = x + (wv > 0 ? wsum[wv - 1] : 0);
    cntA[(size_t)b * GSC + t] = incl - v;       // in-place exclusive base
    if (t == GSC - 1) btot[b] = incl;
}

// ---------------- exclusive scan of bucket totals -> bbase, 3 types ----------------
__global__ __launch_bounds__(1024) void scan_buckets3(
    const int* __restrict__ bt0, int nbk0, int* __restrict__ bb0,
    const int* __restrict__ bt1, int nbk1, int* __restrict__ bb1,
    const int* __restrict__ bt2, int nbk2, int* __restrict__ bb2)
{
    const int* btot; int nbk; int* bbase;
    if (blockIdx.x == 0) { btot = bt0; nbk = nbk0; bbase = bb0; }
    else if (blockIdx.x == 1) { btot = bt1; nbk = nbk1; bbase = bb1; }
    else { btot = bt2; nbk = nbk2; bbase = bb2; }
    int t = threadIdx.x, lane = t & 63, wv = t >> 6;
    __shared__ int wsum[16];
    int v = (t < nbk) ? btot[t] : 0;
    int x = v;
    #pragma unroll
    for (int off = 1; off < 64; off <<= 1) { int u = __shfl_up(x, off, 64); if (lane >= off) x += u; }
    if (lane == 63) wsum[wv] = x;
    __syncthreads();
    if (wv == 0 && lane < 16) {
        int w = wsum[lane];
        #pragma unroll
        for (int off = 1; off < 16; off <<= 1) { int u = __shfl_up(w, off, 64); if (lane >= off) w += u; }
        wsum[lane] = w;
    }
    __syncthreads();
    int incl = x + (wv > 0 ? wsum[wv - 1] : 0);
    if (t <= nbk) bbase[t] = incl - v;
}

// ---------------- pass B: scatter (src,dst) into bucket-grouped ebuf, 3 types ----------------
__global__ __launch_bounds__(256) void bucket_scatter3(
    const int* __restrict__ s0, const int* __restrict__ d0, int E0, int nbk0,
    const int* __restrict__ ba0, const int* __restrict__ bb0, int2* __restrict__ eb0,
    const int* __restrict__ s1, const int* __restrict__ d1, int E1, int nbk1,
    const int* __restrict__ ba1, const int* __restrict__ bb1, int2* __restrict__ eb1,
    const int* __restrict__ s2, const int* __restrict__ d2, int E2, int nbk2,
    const int* __restrict__ ba2, const int* __restrict__ bb2, int2* __restrict__ eb2)
{
    const int *src, *dst, *basesA, *bbase; int E, nbk; int2* ebuf;
    if (blockIdx.y == 0) { src = s0; dst = d0; E = E0; nbk = nbk0; basesA = ba0; bbase = bb0; ebuf = eb0; }
    else if (blockIdx.y == 1) { src = s1; dst = d1; E = E1; nbk = nbk1; basesA = ba1; bbase = bb1; ebuf = eb1; }
    else { src = s2; dst = d2; E = E2; nbk = nbk2; basesA = ba2; bbase = bb2; ebuf = eb2; }
    __shared__ int cur[NBK_MAX];
    for (int i = threadIdx.x; i < nbk; i += 256)
        cur[i] = bbase[i] + basesA[(size_t)i * GSC + blockIdx.x];
    __syncthreads();
    int chunk = (E + GSC - 1) / GSC;
    int i0 = blockIdx.x * chunk, i1 = min(E, i0 + chunk);
    for (int i = i0 + threadIdx.x; i < i1; i += 256) {
        int d = dst[i];
        int pos = atomicAdd(&cur[d >> 6], 1);
        ebuf[pos] = make_int2(src[i], d);
    }
}

// ---------------- per-bucket exact CSR from bucket-grouped edges, 3 types ----------------
__global__ __launch_bounds__(256) void csrify3(
    const int2* __restrict__ eb0, const int* __restrict__ bb0, int M0, int E0, int nbk0,
    int* __restrict__ rp0, int* __restrict__ cs0,
    const int2* __restrict__ eb1, const int* __restrict__ bb1, int M1, int E1, int nbk1,
    int* __restrict__ rp1, int* __restrict__ cs1,
    const int2* __restrict__ eb2, const int* __restrict__ bb2, int M2, int E2, int nbk2,
    int* __restrict__ rp2, int* __restrict__ cs2)
{
    const int2* ebuf; const int* bbase; int M, E, nbk; int *rp, *csr;
    if (blockIdx.y == 0) { ebuf = eb0; bbase = bb0; M = M0; E = E0; nbk = nbk0; rp = rp0; csr = cs0; }
    else if (blockIdx.y == 1) { ebuf = eb1; bbase = bb1; M = M1; E = E1; nbk = nbk1; rp = rp1; csr = cs1; }
    else { ebuf = eb2; bbase = bb2; M = M2; E = E2; nbk = nbk2; rp = rp2; csr = cs2; }
    if ((int)blockIdx.x >= nbk) return;
    __shared__ int hist[64], cur[64];
    int t = threadIdx.x;
    if (t < 64) hist[t] = 0;
    __syncthreads();
    int e0 = bbase[blockIdx.x], e1 = bbase[blockIdx.x + 1];
    for (int e = e0 + t; e < e1; e += 256)
        atomicAdd(&hist[ebuf[e].y & 63], 1);
    __syncthreads();
    if (t < 64) {
        int x = hist[t];
        #pragma unroll
        for (int off = 1; off < 64; off <<= 1) { int u = __shfl_up(x, off, 64); if (t >= off) x += u; }
        int ex = x - hist[t];
        cur[t] = ex;
        int row = (blockIdx.x << 6) + t;
        if (row < M) rp[row] = e0 + ex;
    }
    if (blockIdx.x == 0 && t == 0) rp[M] = E;
    __syncthreads();
    for (int e = e0 + t; e < e1; e += 256) {
        int2 p = ebuf[e];
        int pos = atomicAdd(&cur[p.y & 63], 1);
        csr[e0 + pos] = p.x;
    }
}

// ---------------- elementwise add (bias sums) ----------------
__global__ void add2_kernel(const float* __restrict__ a, const float* __restrict__ b,
                            float* __restrict__ o, int n) {
    int i = blockIdx.x * blockDim.x + threadIdx.x;
    if (i < n) o[i] = a[i] + b[i];
}

// ---------------- f32 -> bf16 + fp8 dual conversion (HW encode) ----------------
__global__ void cvt_dual_kernel(const float* __restrict__ x, ushort* __restrict__ ob,
                                unsigned char* __restrict__ o8, int n4) {
    int i = blockIdx.x * blockDim.x + threadIdx.x;
    if (i >= n4) return;
    float4 v = ((const float4*)x)[i];
    ushort4 rb;
    rb.x = f2bf(v.x); rb.y = f2bf(v.y); rb.z = f2bf(v.z); rb.w = f2bf(v.w);
    ((ushort4*)ob)[i] = rb;
    unsigned lo = fp8enc2(v.x, v.y);
    unsigned hi = fp8enc2(v.z, v.w);
    ((unsigned int*)o8)[i] = lo | (hi << 16);
}

// ---------------- weight prep: Wt[n][k] = bf16(Wa[k][n] (+Wb[k][n])) ----------------
__global__ void wprep_kernel(
    const float* __restrict__ Wa0, const float* __restrict__ Wb0, ushort* __restrict__ Wt0,
    const float* __restrict__ Wa1, ushort* __restrict__ Wt1,
    const float* __restrict__ Wa2, ushort* __restrict__ Wt2,
    const float* __restrict__ Wa3, ushort* __restrict__ Wt3,
    const float* __restrict__ Wa4, ushort* __restrict__ Wt4)
{
    const float* Wa; const float* Wb = nullptr; ushort* Wt;
    switch (blockIdx.x) {
        case 0: Wa = Wa0; Wb = Wb0; Wt = Wt0; break;
        case 1: Wa = Wa1; Wt = Wt1; break;
        case 2: Wa = Wa2; Wt = Wt2; break;
        case 3: Wa = Wa3; Wt = Wt3; break;
        default: Wa = Wa4; Wt = Wt4; break;
    }
    for (int idx = threadIdx.x; idx < 128 * 128; idx += 256) {
        int n = idx >> 7, k = idx & 127;
        float v = Wa[k * 128 + n];
        if (Wb) v += Wb[k * 128 + n];
        Wt[idx] = f2bf(v);
    }
}

// ---------------- graph boundaries via binary search (batch is sorted) ----------------
__global__ void bounds_kernel(const int* __restrict__ bu, int nu,
                              const int* __restrict__ bd, int nd,
                              int* __restrict__ bndu, int* __restrict__ bndd)
{
    const int* b = blockIdx.x == 0 ? bu : bd;
    int        n = blockIdx.x == 0 ? nu : nd;
    int*       o = blockIdx.x == 0 ? bndu : bndd;
    int g = threadIdx.x;
    if (g > NG) return;
    int lo = 0, hi = n;
    while (lo < hi) { int m = (lo + hi) >> 1; if (b[m] < g) lo = m + 1; else hi = m; }
    o[g] = lo;
}

// 8-deep fp8 gather accumulate with HW pair decode (rows 128 fp8 = 128B; lane covers 2 cols)
#define GATHER8(J)                                                                   \
    {                                                                                \
        ushort w0 = *(const ushort*)&xf8[(size_t)csr[(J) + 0] * 128 + lane * 2];     \
        ushort w1 = *(const ushort*)&xf8[(size_t)csr[(J) + 1] * 128 + lane * 2];     \
        ushort w2 = *(const ushort*)&xf8[(size_t)csr[(J) + 2] * 128 + lane * 2];     \
        ushort w3 = *(const ushort*)&xf8[(size_t)csr[(J) + 3] * 128 + lane * 2];     \
        ushort w4 = *(const ushort*)&xf8[(size_t)csr[(J) + 4] * 128 + lane * 2];     \
        ushort w5 = *(const ushort*)&xf8[(size_t)csr[(J) + 5] * 128 + lane * 2];     \
        ushort w6 = *(const ushort*)&xf8[(size_t)csr[(J) + 6] * 128 + lane * 2];     \
        ushort w7 = *(const ushort*)&xf8[(size_t)csr[(J) + 7] * 128 + lane * 2];     \
        f32x2 p0 = fp8pair(w0), p1 = fp8pair(w1), p2 = fp8pair(w2), p3 = fp8pair(w3);\
        f32x2 p4 = fp8pair(w4), p5 = fp8pair(w5), p6 = fp8pair(w6), p7 = fp8pair(w7);\
        sx += (p0[0] + p1[0]) + (p2[0] + p3[0]) + (p4[0] + p5[0]) + (p6[0] + p7[0]); \
        sy += (p0[1] + p1[1]) + (p2[1] + p3[1]) + (p4[1] + p5[1]) + (p6[1] + p7[1]); \
    }

// ---------------- CSR mean aggregation (3 types, fp8 gather -> bf16 means) ----------------
__global__ __launch_bounds__(256) void agg3_kernel(
    const unsigned char* __restrict__ x0, const int* __restrict__ rpa, const int* __restrict__ csa, int Ma, ushort* __restrict__ ma,
    const unsigned char* __restrict__ x1, const int* __restrict__ rpb, const int* __restrict__ csb, int Mb, ushort* __restrict__ mb,
    const unsigned char* __restrict__ x2, const int* __restrict__ rpc, const int* __restrict__ csc, int Mc, ushort* __restrict__ mc)
{
    const unsigned char* xf8; const int *rp, *csr; int M; ushort* mean;
    if (blockIdx.y == 0) { xf8 = x0; rp = rpa; csr = csa; M = Ma; mean = ma; }
    else if (blockIdx.y == 1) { xf8 = x1; rp = rpb; csr = csb; M = Mb; mean = mb; }
    else { xf8 = x2; rp = rpc; csr = csc; M = Mc; mean = mc; }
    int wave = threadIdx.x >> 6, lane = threadIdx.x & 63;
    int row = blockIdx.x * 4 + wave;
    if (row >= M) return;
    int s0 = rp[row], s1 = rp[row + 1];
    float sx = 0.f, sy = 0.f;
    int j = s0;
    for (; j + 8 <= s1; j += 8) GATHER8(j)
    for (; j < s1; ++j) {
        ushort w = *(const ushort*)&xf8[(size_t)csr[j] * 128 + lane * 2];
        f32x2 p = fp8pair(w);
        sx += p[0]; sy += p[1];
    }
    int deg = s1 - s0;
    float sc = 1.f / (float)(deg > 1 ? deg : 1);
    unsigned int pk = (unsigned int)f2bf(sx * sc) | ((unsigned int)f2bf(sy * sc) << 16);
    *(unsigned int*)&mean[(size_t)row * 128 + lane * 2] = pk;
}

// ---------------- MFMA multi-term GEMM: C = relu(sum A_t @ W_t + bias) -> fp8 ----------------
template<int NA>
__global__ __launch_bounds__(256) void gemm_mfma(
    const ushort* __restrict__ A0, const ushort* __restrict__ A1, const ushort* __restrict__ A2,
    const ushort* __restrict__ Wt0, const ushort* __restrict__ Wt1, const ushort* __restrict__ Wt2,
    int M, const float* __restrict__ bias, unsigned char* __restrict__ C)
{
    int wave = threadIdx.x >> 6, lane = threadIdx.x & 63;
    int row0 = blockIdx.x * 64 + wave * 16;
    int r  = lane & 15;
    int kg = lane >> 4;
    f32x4 acc[8];
    #pragma unroll
    for (int nt = 0; nt < 8; ++nt) acc[nt] = (f32x4){0.f, 0.f, 0.f, 0.f};

    int arow = row0 + r;
    int arow_c = arow < M ? arow : 0;
    #pragma unroll
    for (int term = 0; term < NA; ++term) {
        const ushort* A  = (term == 0) ? A0  : (term == 1 ? A1  : A2);
        const ushort* Wt = (term == 0) ? Wt0 : (term == 1 ? Wt1 : Wt2);
        #pragma unroll
        for (int kk = 0; kk < 4; ++kk) {
            bf16x8 a = *(const bf16x8*)&A[(size_t)arow_c * 128 + kk * 32 + kg * 8];
            #pragma unroll
            for (int nt = 0; nt < 8; ++nt) {
                bf16x8 b = *(const bf16x8*)&Wt[(size_t)(nt * 16 + r) * 128 + kk * 32 + kg * 8];
                acc[nt] = __builtin_amdgcn_mfma_f32_16x16x32_bf16(a, b, acc[nt], 0, 0, 0);
            }
        }
    }

    #pragma unroll
    for (int nt = 0; nt < 8; ++nt) {
        int col = nt * 16 + r;
        float bv = bias[col];
        #pragma unroll
        for (int j = 0; j < 4; ++j) {
            int orow = row0 + kg * 4 + j;
            if (orow < M) {
                float v = fmaxf(acc[nt][j] + bv, 0.f);
                C[(size_t)orow * 128 + col] = fp8enc1(v);
            }
        }
    }
}

// ---------------- fused layer-2 agg + per-graph pool (4 rows/wave, fp8, replicated, 3 types) ----------------
__global__ __launch_bounds__(256) void aggpool3_kernel(
    const unsigned char* __restrict__ x0, const int* __restrict__ rpa, const int* __restrict__ csa,
    const int* __restrict__ ba, int Ma, float* __restrict__ pa,
    const unsigned char* __restrict__ x1, const int* __restrict__ rpb, const int* __restrict__ csb,
    const int* __restrict__ bb, int Mb, float* __restrict__ pb,
    const unsigned char* __restrict__ x2, const int* __restrict__ rpc, const int* __restrict__ csc,
    const int* __restrict__ bc, int Mc, float* __restrict__ pc)
{
    const unsigned char* xf8; const int *rp, *csr, *batch; int M; float* pool;
    if (blockIdx.y == 0) { xf8 = x0; rp = rpa; csr = csa; batch = ba; M = Ma; pool = pa; }
    else if (blockIdx.y == 1) { xf8 = x1; rp = rpb; csr = csb; batch = bb; M = Mb; pool = pb; }
    else { xf8 = x2; rp = rpc; csr = csc; batch = bc; M = Mc; pool = pc; }
    int wave = threadIdx.x >> 6, lane = threadIdx.x & 63;
    int r0 = (blockIdx.x * 4 + wave) * 4;
    if (r0 >= M) return;
    int r1 = min(M, r0 + 4);
    float* p = pool + (size_t)(blockIdx.x & (REP - 1)) * NG * 128;
    float ax = 0.f, ay = 0.f;
    int curg = batch[r0];
    for (int row = r0; row < r1; ++row) {
        int g = batch[row];
        if (g != curg) {
            atomicAdd(&p[curg * 128 + lane * 2],     ax);
            atomicAdd(&p[curg * 128 + lane * 2 + 1], ay);
            ax = 0.f; ay = 0.f; curg = g;
        }
        int s0 = rp[row], s1 = rp[row + 1];
        float sx = 0.f, sy = 0.f;
        int j = s0;
        for (; j + 8 <= s1; j += 8) GATHER8(j)
        for (; j < s1; ++j) {
            ushort w = *(const ushort*)&xf8[(size_t)csr[j] * 128 + lane * 2];
            f32x2 pv = fp8pair(w);
            sx += pv[0]; sy += pv[1];
        }
        int deg = s1 - s0;
        float sc = 1.f / (float)(deg > 1 ? deg : 1);
        ax += sx * sc; ay += sy * sc;
    }
    atomicAdd(&p[curg * 128 + lane * 2],     ax);
    atomicAdd(&p[curg * 128 + lane * 2 + 1], ay);
}

// ---------------- 2-way per-graph row-sum pool over fp8 rows (batch sorted) ----------------
__global__ __launch_bounds__(256) void pool2_kernel(
    const unsigned char* __restrict__ u1f, const unsigned char* __restrict__ d1f,
    const int* __restrict__ bndu, const int* __restrict__ bndd,
    float* __restrict__ pu1, float* __restrict__ pd1)
{
    const unsigned char* xf8; const int* bnd; float* pool;
    if (blockIdx.y == 0) { xf8 = u1f; bnd = bndu; pool = pu1; }
    else { xf8 = d1f; bnd = bndd; pool = pd1; }
    int g = blockIdx.x;
    int lo = bnd[g], hi = bnd[g + 1];
    int c2 = threadIdx.x & 63, half = threadIdx.x >> 6;
    float sx = 0.f, sy = 0.f;
    for (int r = lo + half; r < hi; r += 4) {
        ushort w = *(const ushort*)&xf8[(size_t)r * 128 + c2 * 2];
        f32x2 p = fp8pair(w);
        sx += p[0]; sy += p[1];
    }
    __shared__ float ls[256 * 2];
    ls[threadIdx.x * 2]     = sx;
    ls[threadIdx.x * 2 + 1] = sy;
    __syncthreads();
    if (half == 0) {
        float ox = ls[c2 * 2] + ls[(64 + c2) * 2] + ls[(128 + c2) * 2] + ls[(192 + c2) * 2];
        float oy = ls[c2 * 2 + 1] + ls[(64 + c2) * 2 + 1] + ls[(128 + c2) * 2 + 1] + ls[(192 + c2) * 2 + 1];
        pool[g * 128 + c2 * 2]     = ox;
        pool[g * 128 + c2 * 2 + 1] = oy;
    }
}

// ---------------- final: layer-2 matmuls at graph level + MLP + log_softmax ----------------
__global__ __launch_bounds__(128) void final_kernel(
    const float* __restrict__ pmdu, const float* __restrict__ pmuu, const float* __restrict__ pmud,
    const float* __restrict__ pu1,  const float* __restrict__ pd1,
    const int* __restrict__ bndu, const int* __restrict__ bndd,
    const float* __restrict__ Wl2_du, const float* __restrict__ bl2_du, const float* __restrict__ Wr2_du,
    const float* __restrict__ Wl2_uu, const float* __restrict__ bl2_uu, const float* __restrict__ Wr2_uu,
    const float* __restrict__ Wl2_ud, const float* __restrict__ bl2_ud, const float* __restrict__ Wr2_ud,
    const float* __restrict__ W1, const float* __restrict__ b1,
    const float* __restrict__ W2, const float* __restrict__ b2,
    float* __restrict__ out)
{
    int g = blockIdx.x, t = threadIdx.x;
    __shared__ float smdu[128], smuu[128], smud[128], su1[128], sd1[128];
    __shared__ float xrow[256], h[128], lg[2];
    float vdu = 0.f, vuu = 0.f, vud = 0.f;
    #pragma unroll
    for (int r = 0; r < REP; ++r) {
        vdu += pmdu[(size_t)r * NG * 128 + g * 128 + t];
        vuu += pmuu[(size_t)r * NG * 128 + g * 128 + t];
        vud += pmud[(size_t)r * NG * 128 + g * 128 + t];
    }
    smdu[t] = vdu;
    smuu[t] = vuu;
    smud[t] = vud;
    su1[t]  = pu1[g * 128 + t];
    sd1[t]  = pd1[g * 128 + t];
    __syncthreads();
    float ncu = (float)(bndu[g + 1] - bndu[g]);
    float ncd = (float)(bndd[g + 1] - bndd[g]);
    float cu = ncu > 1.f ? ncu : 1.f, cd = ncd > 1.f ? ncd : 1.f;
    float accu = ncu * (bl2_du[t] + bl2_uu[t]);
    float accd = ncd * bl2_ud[t];
    for (int k = 0; k < 128; ++k) {
        accu += smdu[k] * Wl2_du[k * 128 + t]
              + smuu[k] * Wl2_uu[k * 128 + t]
              + su1[k]  * (Wr2_du[k * 128 + t] + Wr2_uu[k * 128 + t]);
        accd += smud[k] * Wl2_ud[k * 128 + t]
              + sd1[k]  * Wr2_ud[k * 128 + t];
    }
    xrow[t]       = accu / cu;
    xrow[128 + t] = accd / cd;
    __syncthreads();
    float hh = b1[t];
    for (int k = 0; k < 256; ++k) hh += xrow[k] * W1[k * 128 + t];
    h[t] = fmaxf(hh, 0.f);
    __syncthreads();
    if (t < 2) {
        float l = b2[t];
        for (int k = 0; k < 128; ++k) l += h[k] * W2[k * 2 + t];
        lg[t] = l;
    }
    __syncthreads();
    if (t == 0) {
        float m = fmaxf(lg[0], lg[1]);
        float lse = m + logf(expf(lg[0] - m) + expf(lg[1] - m));
        out[g * 2 + 0] = lg[0] - lse;
        out[g * 2 + 1] = lg[1] - lse;
    }
}

extern "C" void kernel_launch(void* const* d_in, const int* in_sizes, int n_in,
                              void* d_out, int out_size, void* d_ws, size_t ws_size,
                              hipStream_t stream)
{
    const float* x_user = (const float*)d_in[0];
    const float* x_drug = (const float*)d_in[1];
    const int* ei_ud = (const int*)d_in[2];
    const int* ei_du = (const int*)d_in[3];
    const int* ei_uu = (const int*)d_in[4];
    const int* batch_u = (const int*)d_in[5];
    const int* batch_d = (const int*)d_in[6];
    const float* Wl1_ud = (const float*)d_in[7];  const float* bl1_ud = (const float*)d_in[8];  const float* Wr1_ud = (const float*)d_in[9];
    const float* Wl1_du = (const float*)d_in[10]; const float* bl1_du = (const float*)d_in[11]; const float* Wr1_du = (const float*)d_in[12];
    const float* Wl1_uu = (const float*)d_in[13]; const float* bl1_uu = (const float*)d_in[14]; const float* Wr1_uu = (const float*)d_in[15];
    const float* Wl2_ud = (const float*)d_in[16]; const float* bl2_ud = (const float*)d_in[17]; const float* Wr2_ud = (const float*)d_in[18];
    const float* Wl2_du = (const float*)d_in[19]; const float* bl2_du = (const float*)d_in[20]; const float* Wr2_du = (const float*)d_in[21];
    const float* Wl2_uu = (const float*)d_in[22]; const float* bl2_uu = (const float*)d_in[23]; const float* Wr2_uu = (const float*)d_in[24];
    const float* W1 = (const float*)d_in[25]; const float* b1 = (const float*)d_in[26];
    const float* W2 = (const float*)d_in[27]; const float* b2 = (const float*)d_in[28];
    (void)n_in; (void)out_size; (void)ws_size;

    const int Nu = in_sizes[0] / 128;
    const int Nd = in_sizes[1] / 128;
    const int E_ud = in_sizes[2] / 2;
    const int E_du = in_sizes[3] / 2;
    const int E_uu = in_sizes[4] / 2;
    const int nbk_u = (Nu + 63) >> 6;
    const int nbk_d = (Nd + 63) >> 6;
    const int nbk_max = nbk_u > nbk_d ? nbk_u : nbk_d;
    const int Nmax = Nu > Nd ? Nu : Nd;

    char* ws = (char*)d_ws;
    size_t off = 0;
    auto alloc = [&](size_t bytes) -> void* {
        void* p = ws + off;
        off = (off + bytes + 255) & ~(size_t)255;
        return p;
    };
    int2* ebuf_ud = (int2*)alloc((size_t)E_ud * 8);
    int2* ebuf_du = (int2*)alloc((size_t)E_du * 8);
    int2* ebuf_uu = (int2*)alloc((size_t)E_uu * 8);
    int* cntA_ud = (int*)alloc((size_t)NBK_MAX * GSC * 4);
    int* cntA_du = (int*)alloc((size_t)NBK_MAX * GSC * 4);
    int* cntA_uu = (int*)alloc((size_t)NBK_MAX * GSC * 4);
    int* btot_ud = (int*)alloc((size_t)NBK_MAX * 4);
    int* btot_du = (int*)alloc((size_t)NBK_MAX * 4);
    int* btot_uu = (int*)alloc((size_t)NBK_MAX * 4);
    int* bbase_ud = (int*)alloc((size_t)(NBK_MAX + 1) * 4);
    int* bbase_du = (int*)alloc((size_t)(NBK_MAX + 1) * 4);
    int* bbase_uu = (int*)alloc((size_t)(NBK_MAX + 1) * 4);
    int* csr_ud = (int*)alloc((size_t)E_ud * 4);
    int* csr_du = (int*)alloc((size_t)E_du * 4);
    int* csr_uu = (int*)alloc((size_t)E_uu * 4);
    int* rp_ud = (int*)alloc((size_t)(Nd + 1) * 4);
    int* rp_du = (int*)alloc((size_t)(Nu + 1) * 4);
    int* rp_uu = (int*)alloc((size_t)(Nu + 1) * 4);
    ushort* xb_u = (ushort*)alloc((size_t)Nu * 128 * 2);    // bf16 (MFMA A-operand)
    ushort* xb_d = (ushort*)alloc((size_t)Nd * 128 * 2);
    unsigned char* xf8_u = (unsigned char*)alloc((size_t)Nu * 128);   // fp8 gather tables
    unsigned char* xf8_d = (unsigned char*)alloc((size_t)Nd * 128);
    // layer-1 mean buffers overlay the ebufs (dead after csrify)
    ushort* mean_du = (ushort*)ebuf_du;   // [Nu,128] bf16
    ushort* mean_uu = (ushort*)ebuf_uu;   // [Nu,128]
    ushort* mean_ud = (ushort*)ebuf_ud;   // [Nd,128]
    unsigned char* u1f = (unsigned char*)alloc((size_t)Nu * 128);   // layer-1 out, fp8
    unsigned char* d1f = (unsigned char*)alloc((size_t)Nd * 128);
    float* pmdu = (float*)alloc((size_t)REP * NG * 128 * 4);
    float* pmuu = (float*)alloc((size_t)REP * NG * 128 * 4);
    float* pmud = (float*)alloc((size_t)REP * NG * 128 * 4);
    char* zero2_beg = (char*)pmdu;
    char* zero2_end = ws + off;
    float* pu1  = (float*)alloc(NG * 128 * 4);
    float* pd1  = (float*)alloc(NG * 128 * 4);
    int* bnd_u = (int*)alloc((NG + 1) * 4);
    int* bnd_d = (int*)alloc((NG + 1) * 4);
    ushort* Wt_ru  = (ushort*)alloc(128 * 128 * 2);
    ushort* Wt_ldu = (ushort*)alloc(128 * 128 * 2);
    ushort* Wt_luu = (ushort*)alloc(128 * 128 * 2);
    ushort* Wt_rud = (ushort*)alloc(128 * 128 * 2);
    ushort* Wt_lud = (ushort*)alloc(128 * 128 * 2);
    float* b1s_u  = (float*)alloc(128 * 4);

    const int* dst_ud = ei_ud + E_ud;
    const int* dst_du = ei_du + E_du;
    const int* dst_uu = ei_uu + E_uu;

    // ---- CSR build via LDS bucket sort (zero device atomics), 3 types per launch ----
    bucket_count3<<<dim3(GSC, 3), 256, 0, stream>>>(
        dst_ud, E_ud, nbk_d, cntA_ud,
        dst_du, E_du, nbk_u, cntA_du,
        dst_uu, E_uu, nbk_u, cntA_uu);
    scan_blocks3<<<dim3(nbk_max, 3), GSC, 0, stream>>>(
        cntA_ud, nbk_d, btot_ud,
        cntA_du, nbk_u, btot_du,
        cntA_uu, nbk_u, btot_uu);
    scan_buckets3<<<3, 1024, 0, stream>>>(
        btot_ud, nbk_d, bbase_ud,
        btot_du, nbk_u, bbase_du,
        btot_uu, nbk_u, bbase_uu);
    bucket_scatter3<<<dim3(GSC, 3), 256, 0, stream>>>(
        ei_ud, dst_ud, E_ud, nbk_d, cntA_ud, bbase_ud, ebuf_ud,
        ei_du, dst_du, E_du, nbk_u, cntA_du, bbase_du, ebuf_du,
        ei_uu, dst_uu, E_uu, nbk_u, cntA_uu, bbase_uu, ebuf_uu);
    csrify3<<<dim3(nbk_max, 3), 256, 0, stream>>>(
        ebuf_ud, bbase_ud, Nd, E_ud, nbk_d, rp_ud, csr_ud,
        ebuf_du, bbase_du, Nu, E_du, nbk_u, rp_du, csr_du,
        ebuf_uu, bbase_uu, Nu, E_uu, nbk_u, rp_uu, csr_uu);

    // ---- graph boundaries, bf16+fp8 inputs, weight prep, pm memset ----
    bounds_kernel<<<2, NG + 1, 0, stream>>>(batch_u, Nu, batch_d, Nd, bnd_u, bnd_d);
    cvt_dual_kernel<<<(Nu * 32 + 255) / 256, 256, 0, stream>>>(x_user, xb_u, xf8_u, Nu * 32);
    cvt_dual_kernel<<<(Nd * 32 + 255) / 256, 256, 0, stream>>>(x_drug, xb_d, xf8_d, Nd * 32);
    wprep_kernel<<<5, 256, 0, stream>>>(Wr1_du, Wr1_uu, Wt_ru,
                                        Wl1_du, Wt_ldu, Wl1_uu, Wt_luu,
                                        Wr1_ud, Wt_rud, Wl1_ud, Wt_lud);
    add2_kernel<<<1, 128, 0, stream>>>(bl1_du, bl1_uu, b1s_u, 128);
    hipMemsetAsync(zero2_beg, 0, (size_t)(zero2_end - zero2_beg), stream);

    // ---- layer-1 aggregation (fp8 gather, 3 types, one launch; means overlay dead ebufs) ----
    agg3_kernel<<<dim3((Nmax + 3) / 4, 3), 256, 0, stream>>>(
        xf8_d, rp_du, csr_du, Nu, mean_du,
        xf8_u, rp_uu, csr_uu, Nu, mean_uu,
        xf8_u, rp_ud, csr_ud, Nd, mean_ud);

    // ---- layer-1 MFMA GEMMs -> fp8 ----
    gemm_mfma<3><<<(Nu + 63) / 64, 256, 0, stream>>>(xb_u, mean_du, mean_uu,
                                                     Wt_ru, Wt_ldu, Wt_luu, Nu, b1s_u, u1f);
    gemm_mfma<2><<<(Nd + 63) / 64, 256, 0, stream>>>(xb_d, mean_ud, nullptr,
                                                     Wt_rud, Wt_lud, nullptr, Nd, bl1_ud, d1f);

    // ---- layer 2: fused CSR-mean + per-graph pool (fp8 gather, replicated, one launch) ----
    aggpool3_kernel<<<dim3((Nmax + 15) / 16, 3), 256, 0, stream>>>(
        d1f, rp_du, csr_du, batch_u, Nu, pmdu,
        u1f, rp_uu, csr_uu, batch_u, Nu, pmuu,
        u1f, rp_ud, csr_ud, batch_d, Nd, pmud);

    // ---- root-term pools (direct store, fp8 stream) ----
    pool2_kernel<<<dim3(NG, 2), 256, 0, stream>>>(u1f, d1f, bnd_u, bnd_d, pu1, pd1);

    // ---- graph-level layer-2 matmuls + MLP + log_softmax ----
    final_kernel<<<NG, 128, 0, stream>>>(pmdu, pmuu, pmud, pu1, pd1, bnd_u, bnd_d,
                                         Wl2_du, bl2_du, Wr2_du,
                                         Wl2_uu, bl2_uu, Wr2_uu,
                                         Wl2_ud, bl2_ud, Wr2_ud,
                                         W1, b1, W2, b2, (float*)d_out);
}

// Round 15
// 566.987 us; speedup vs baseline: 1.1851x; 1.0184x over previous
//
#include <hip/hip_runtime.h>

#define NG 64
#define REP 8          // aggpool replicas
#define GSC 512        // scatter grid blocks
#define NBK_MAX 1024   // max buckets (N <= 65536)

typedef __bf16 bf16x8 __attribute__((ext_vector_type(8)));
typedef float  f32x4  __attribute__((ext_vector_type(4)));
typedef float  f32x2  __attribute__((ext_vector_type(2)));

__device__ __forceinline__ ushort f2bf(float f) {
    unsigned int b = __float_as_uint(f);
    b += 0x7fffu + ((b >> 16) & 1u);   // RTNE
    return (ushort)(b >> 16);
}

// ---- fp8 e4m3 (OCP) via gfx950 HW converters ----
__device__ __forceinline__ f32x2 fp8pair(unsigned w) {
    return __builtin_amdgcn_cvt_pk_f32_fp8((int)w, false);
}
__device__ __forceinline__ unsigned fp8enc2(float a, float b) {
    return (unsigned)__builtin_amdgcn_cvt_pk_fp8_f32(a, b, 0, false) & 0xffffu;
}
__device__ __forceinline__ unsigned char fp8enc1(float a) {
    return (unsigned char)(__builtin_amdgcn_cvt_pk_fp8_f32(a, 0.f, 0, false) & 0xff);
}

// ---------------- pass A: per-block bucket counts (LDS int hist), 3 types ----------------
__global__ __launch_bounds__(256) void bucket_count3(
    const int* __restrict__ d0, int E0, int nbk0, int* __restrict__ c0,
    const int* __restrict__ d1, int E1, int nbk1, int* __restrict__ c1,
    const int* __restrict__ d2, int E2, int nbk2, int* __restrict__ c2)
{
    const int* dst; int E, nbk; int* cntA;
    if (blockIdx.y == 0) { dst = d0; E = E0; nbk = nbk0; cntA = c0; }
    else if (blockIdx.y == 1) { dst = d1; E = E1; nbk = nbk1; cntA = c1; }
    else { dst = d2; E = E2; nbk = nbk2; cntA = c2; }
    __shared__ int h[NBK_MAX];
    for (int i = threadIdx.x; i < nbk; i += 256) h[i] = 0;
    __syncthreads();
    int chunk = (E + GSC - 1) / GSC;
    int i0 = blockIdx.x * chunk, i1 = min(E, i0 + chunk);
    for (int i = i0 + threadIdx.x; i < i1; i += 256)
        atomicAdd(&h[dst[i] >> 6], 1);
    __syncthreads();
    for (int i = threadIdx.x; i < nbk; i += 256)
        cntA[(size_t)i * GSC + blockIdx.x] = h[i];
}

// ---------------- in-place scan over blocks per bucket, 3 types ----------------
__global__ __launch_bounds__(GSC) void scan_blocks3(
    int* __restrict__ c0, int nbk0, int* __restrict__ bt0,
    int* __restrict__ c1, int nbk1, int* __restrict__ bt1,
    int* __restrict__ c2, int nbk2, int* __restrict__ bt2)
{
    int* cntA; int nbk; int* btot;
    if (blockIdx.y == 0) { cntA = c0; nbk = nbk0; btot = bt0; }
    else if (blockIdx.y == 1) { cntA = c1; nbk = nbk1; btot = bt1; }
    else { cntA = c2; nbk = nbk2; btot = bt2; }
    int b = blockIdx.x;
    if (b >= nbk) return;
    int t = threadIdx.x, lane = t & 63, wv = t >> 6;   // 8 waves
    __shared__ int wsum[8];
    int v = cntA[(size_t)b * GSC + t];
    int x = v;
    #pragma unroll
    for (int off = 1; off < 64; off <<= 1) { int u = __shfl_up(x, off, 64); if (lane >= off) x += u; }
    if (lane == 63) wsum[wv] = x;
    __syncthreads();
    if (wv == 0 && lane < 8) {
        int w = wsum[lane];
        #pragma unroll
        for (int off = 1; off < 8; off <<= 1) { int u = __shfl_up(w, off, 64); if (lane >= off) w += u; }
        wsum[lane] = w;
    }
    __syncthreads();
    int incl = x + (wv > 0 ? wsum[wv - 1] : 0);
    cntA[(size_t)b * GSC + t] = incl - v;       // in-place exclusive base
    if (t == GSC - 1) btot[b] = incl;
}

// ---------------- exclusive scan of bucket totals -> bbase, 3 types ----------------
__global__ __launch_bounds__(1024) void scan_buckets3(
    const int* __restrict__ bt0, int nbk0, int* __restrict__ bb0,
    const int* __restrict__ bt1, int nbk1, int* __restrict__ bb1,
    const int* __restrict__ bt2, int nbk2, int* __restrict__ bb2)
{
    const int* btot; int nbk; int* bbase;
    if (blockIdx.x == 0) { btot = bt0; nbk = nbk0; bbase = bb0; }
    else if (blockIdx.x == 1) { btot = bt1; nbk = nbk1; bbase = bb1; }
    else { btot = bt2; nbk = nbk2; bbase = bb2; }
    int t = threadIdx.x, lane = t & 63, wv = t >> 6;
    __shared__ int wsum[16];
    int v = (t < nbk) ? btot[t] : 0;
    int x = v;
    #pragma unroll
    for (int off = 1; off < 64; off <<= 1) { int u = __shfl_up(x, off, 64); if (lane >= off) x += u; }
    if (lane == 63) wsum[wv] = x;
    __syncthreads();
    if (wv == 0 && lane < 16) {
        int w = wsum[lane];
        #pragma unroll
        for (int off = 1; off < 16; off <<= 1) { int u = __shfl_up(w, off, 64); if (lane >= off) w += u; }
        wsum[lane] = w;
    }
    __syncthreads();
    int incl = x + (wv > 0 ? wsum[wv - 1] : 0);
    if (t <= nbk) bbase[t] = incl - v;
}

// ---------------- pass B: scatter (src,dst) into bucket-grouped ebuf, 3 types ----------------
__global__ __launch_bounds__(256) void bucket_scatter3(
    const int* __restrict__ s0, const int* __restrict__ d0, int E0, int nbk0,
    const int* __restrict__ ba0, const int* __restrict__ bb0, int2* __restrict__ eb0,
    const int* __restrict__ s1, const int* __restrict__ d1, int E1, int nbk1,
    const int* __restrict__ ba1, const int* __restrict__ bb1, int2* __restrict__ eb1,
    const int* __restrict__ s2, const int* __restrict__ d2, int E2, int nbk2,
    const int* __restrict__ ba2, const int* __restrict__ bb2, int2* __restrict__ eb2)
{
    const int *src, *dst, *basesA, *bbase; int E, nbk; int2* ebuf;
    if (blockIdx.y == 0) { src = s0; dst = d0; E = E0; nbk = nbk0; basesA = ba0; bbase = bb0; ebuf = eb0; }
    else if (blockIdx.y == 1) { src = s1; dst = d1; E = E1; nbk = nbk1; basesA = ba1; bbase = bb1; ebuf = eb1; }
    else { src = s2; dst = d2; E = E2; nbk = nbk2; basesA = ba2; bbase = bb2; ebuf = eb2; }
    __shared__ int cur[NBK_MAX];
    for (int i = threadIdx.x; i < nbk; i += 256)
        cur[i] = bbase[i] + basesA[(size_t)i * GSC + blockIdx.x];
    __syncthreads();
    int chunk = (E + GSC - 1) / GSC;
    int i0 = blockIdx.x * chunk, i1 = min(E, i0 + chunk);
    for (int i = i0 + threadIdx.x; i < i1; i += 256) {
        int d = dst[i];
        int pos = atomicAdd(&cur[d >> 6], 1);
        ebuf[pos] = make_int2(src[i], d);
    }
}

// ---------------- per-bucket exact CSR from bucket-grouped edges, 3 types ----------------
__global__ __launch_bounds__(256) void csrify3(
    const int2* __restrict__ eb0, const int* __restrict__ bb0, int M0, int E0, int nbk0,
    int* __restrict__ rp0, int* __restrict__ cs0,
    const int2* __restrict__ eb1, const int* __restrict__ bb1, int M1, int E1, int nbk1,
    int* __restrict__ rp1, int* __restrict__ cs1,
    const int2* __restrict__ eb2, const int* __restrict__ bb2, int M2, int E2, int nbk2,
    int* __restrict__ rp2, int* __restrict__ cs2)
{
    const int2* ebuf; const int* bbase; int M, E, nbk; int *rp, *csr;
    if (blockIdx.y == 0) { ebuf = eb0; bbase = bb0; M = M0; E = E0; nbk = nbk0; rp = rp0; csr = cs0; }
    else if (blockIdx.y == 1) { ebuf = eb1; bbase = bb1; M = M1; E = E1; nbk = nbk1; rp = rp1; csr = cs1; }
    else { ebuf = eb2; bbase = bb2; M = M2; E = E2; nbk = nbk2; rp = rp2; csr = cs2; }
    if ((int)blockIdx.x >= nbk) return;
    __shared__ int hist[64], cur[64];
    int t = threadIdx.x;
    if (t < 64) hist[t] = 0;
    __syncthreads();
    int e0 = bbase[blockIdx.x], e1 = bbase[blockIdx.x + 1];
    for (int e = e0 + t; e < e1; e += 256)
        atomicAdd(&hist[ebuf[e].y & 63], 1);
    __syncthreads();
    if (t < 64) {
        int x = hist[t];
        #pragma unroll
        for (int off = 1; off < 64; off <<= 1) { int u = __shfl_up(x, off, 64); if (t >= off) x += u; }
        int ex = x - hist[t];
        cur[t] = ex;
        int row = (blockIdx.x << 6) + t;
        if (row < M) rp[row] = e0 + ex;
    }
    if (blockIdx.x == 0 && t == 0) rp[M] = E;
    __syncthreads();
    for (int e = e0 + t; e < e1; e += 256) {
        int2 p = ebuf[e];
        int pos = atomicAdd(&cur[p.y & 63], 1);
        csr[e0 + pos] = p.x;
    }
}

// ---------------- prep: wprep (5 jobs) + bias sum + bounds, one launch ----------------
__global__ __launch_bounds__(256) void prep_kernel(
    const float* __restrict__ Wa0, const float* __restrict__ Wb0, ushort* __restrict__ Wt0,
    const float* __restrict__ Wa1, ushort* __restrict__ Wt1,
    const float* __restrict__ Wa2, ushort* __restrict__ Wt2,
    const float* __restrict__ Wa3, ushort* __restrict__ Wt3,
    const float* __restrict__ Wa4, ushort* __restrict__ Wt4,
    const float* __restrict__ ba, const float* __restrict__ bb, float* __restrict__ bo,
    const int* __restrict__ bu, int nu, const int* __restrict__ bd, int nd,
    int* __restrict__ bndu, int* __restrict__ bndd)
{
    if (blockIdx.x < 5) {
        const float* Wa; const float* Wb = nullptr; ushort* Wt;
        switch (blockIdx.x) {
            case 0: Wa = Wa0; Wb = Wb0; Wt = Wt0; break;
            case 1: Wa = Wa1; Wt = Wt1; break;
            case 2: Wa = Wa2; Wt = Wt2; break;
            case 3: Wa = Wa3; Wt = Wt3; break;
            default: Wa = Wa4; Wt = Wt4; break;
        }
        for (int idx = threadIdx.x; idx < 128 * 128; idx += 256) {
            int n = idx >> 7, k = idx & 127;
            float v = Wa[k * 128 + n];
            if (Wb) v += Wb[k * 128 + n];
            Wt[idx] = f2bf(v);
        }
    } else if (blockIdx.x == 5) {
        int t = threadIdx.x;
        if (t < 128) bo[t] = ba[t] + bb[t];
    } else {
        int g = threadIdx.x & 127, which = threadIdx.x >> 7;
        if (g > NG) return;
        const int* b = which == 0 ? bu : bd;
        int        n = which == 0 ? nu : nd;
        int*       o = which == 0 ? bndu : bndd;
        int lo = 0, hi = n;
        while (lo < hi) { int m = (lo + hi) >> 1; if (b[m] < g) lo = m + 1; else hi = m; }
        o[g] = lo;
    }
}

// ---------------- f32 -> bf16 + fp8 dual conversion (2 tensors, one launch) ----------------
__global__ void cvt_dual2_kernel(const float* __restrict__ xu, ushort* __restrict__ obu,
                                 unsigned char* __restrict__ o8u, int n4u,
                                 const float* __restrict__ xd, ushort* __restrict__ obd,
                                 unsigned char* __restrict__ o8d, int n4d)
{
    const float* x; ushort* ob; unsigned char* o8; int n4;
    if (blockIdx.y == 0) { x = xu; ob = obu; o8 = o8u; n4 = n4u; }
    else { x = xd; ob = obd; o8 = o8d; n4 = n4d; }
    int i = blockIdx.x * blockDim.x + threadIdx.x;
    if (i >= n4) return;
    float4 v = ((const float4*)x)[i];
    ushort4 rb;
    rb.x = f2bf(v.x); rb.y = f2bf(v.y); rb.z = f2bf(v.z); rb.w = f2bf(v.w);
    ((ushort4*)ob)[i] = rb;
    unsigned lo = fp8enc2(v.x, v.y);
    unsigned hi = fp8enc2(v.z, v.w);
    ((unsigned int*)o8)[i] = lo | (hi << 16);
}

// 8-deep fp8 gather with int4 index preload + HW pair decode
#define GATHER8(J)                                                                   \
    {                                                                                \
        int4 ia = *(const int4*)&csr[(J)];                                           \
        int4 ib = *(const int4*)&csr[(J) + 4];                                       \
        ushort w0 = *(const ushort*)&xf8[(size_t)ia.x * 128 + lane * 2];             \
        ushort w1 = *(const ushort*)&xf8[(size_t)ia.y * 128 + lane * 2];             \
        ushort w2 = *(const ushort*)&xf8[(size_t)ia.z * 128 + lane * 2];             \
        ushort w3 = *(const ushort*)&xf8[(size_t)ia.w * 128 + lane * 2];             \
        ushort w4 = *(const ushort*)&xf8[(size_t)ib.x * 128 + lane * 2];             \
        ushort w5 = *(const ushort*)&xf8[(size_t)ib.y * 128 + lane * 2];             \
        ushort w6 = *(const ushort*)&xf8[(size_t)ib.z * 128 + lane * 2];             \
        ushort w7 = *(const ushort*)&xf8[(size_t)ib.w * 128 + lane * 2];             \
        f32x2 p0 = fp8pair(w0), p1 = fp8pair(w1), p2 = fp8pair(w2), p3 = fp8pair(w3);\
        f32x2 p4 = fp8pair(w4), p5 = fp8pair(w5), p6 = fp8pair(w6), p7 = fp8pair(w7);\
        sx += (p0[0] + p1[0]) + (p2[0] + p3[0]) + (p4[0] + p5[0]) + (p6[0] + p7[0]); \
        sy += (p0[1] + p1[1]) + (p2[1] + p3[1]) + (p4[1] + p5[1]) + (p6[1] + p7[1]); \
    }

// ---------------- CSR mean aggregation (3 types, fp8 gather -> bf16 means) ----------------
__global__ __launch_bounds__(256) void agg3_kernel(
    const unsigned char* __restrict__ x0, const int* __restrict__ rpa, const int* __restrict__ csa, int Ma, ushort* __restrict__ ma,
    const unsigned char* __restrict__ x1, const int* __restrict__ rpb, const int* __restrict__ csb, int Mb, ushort* __restrict__ mb,
    const unsigned char* __restrict__ x2, const int* __restrict__ rpc, const int* __restrict__ csc, int Mc, ushort* __restrict__ mc)
{
    const unsigned char* xf8; const int *rp, *csr; int M; ushort* mean;
    if (blockIdx.y == 0) { xf8 = x0; rp = rpa; csr = csa; M = Ma; mean = ma; }
    else if (blockIdx.y == 1) { xf8 = x1; rp = rpb; csr = csb; M = Mb; mean = mb; }
    else { xf8 = x2; rp = rpc; csr = csc; M = Mc; mean = mc; }
    int wave = threadIdx.x >> 6, lane = threadIdx.x & 63;
    int row = blockIdx.x * 4 + wave;
    if (row >= M) return;
    int s0 = rp[row], s1 = rp[row + 1];
    float sx = 0.f, sy = 0.f;
    int j = s0;
    for (; j + 8 <= s1; j += 8) GATHER8(j)
    for (; j < s1; ++j) {
        ushort w = *(const ushort*)&xf8[(size_t)csr[j] * 128 + lane * 2];
        f32x2 p = fp8pair(w);
        sx += p[0]; sy += p[1];
    }
    int deg = s1 - s0;
    float sc = 1.f / (float)(deg > 1 ? deg : 1);
    unsigned int pk = (unsigned int)f2bf(sx * sc) | ((unsigned int)f2bf(sy * sc) << 16);
    *(unsigned int*)&mean[(size_t)row * 128 + lane * 2] = pk;
}

// ---------------- MFMA multi-term GEMM: C = relu(sum A_t @ W_t + bias) -> fp8 ----------------
template<int NA>
__global__ __launch_bounds__(256) void gemm_mfma(
    const ushort* __restrict__ A0, const ushort* __restrict__ A1, const ushort* __restrict__ A2,
    const ushort* __restrict__ Wt0, const ushort* __restrict__ Wt1, const ushort* __restrict__ Wt2,
    int M, const float* __restrict__ bias, unsigned char* __restrict__ C)
{
    int wave = threadIdx.x >> 6, lane = threadIdx.x & 63;
    int row0 = blockIdx.x * 64 + wave * 16;
    int r  = lane & 15;
    int kg = lane >> 4;
    f32x4 acc[8];
    #pragma unroll
    for (int nt = 0; nt < 8; ++nt) acc[nt] = (f32x4){0.f, 0.f, 0.f, 0.f};

    int arow = row0 + r;
    int arow_c = arow < M ? arow : 0;
    #pragma unroll
    for (int term = 0; term < NA; ++term) {
        const ushort* A  = (term == 0) ? A0  : (term == 1 ? A1  : A2);
        const ushort* Wt = (term == 0) ? Wt0 : (term == 1 ? Wt1 : Wt2);
        #pragma unroll
        for (int kk = 0; kk < 4; ++kk) {
            bf16x8 a = *(const bf16x8*)&A[(size_t)arow_c * 128 + kk * 32 + kg * 8];
            #pragma unroll
            for (int nt = 0; nt < 8; ++nt) {
                bf16x8 b = *(const bf16x8*)&Wt[(size_t)(nt * 16 + r) * 128 + kk * 32 + kg * 8];
                acc[nt] = __builtin_amdgcn_mfma_f32_16x16x32_bf16(a, b, acc[nt], 0, 0, 0);
            }
        }
    }

    #pragma unroll
    for (int nt = 0; nt < 8; ++nt) {
        int col = nt * 16 + r;
        float bv = bias[col];
        #pragma unroll
        for (int j = 0; j < 4; ++j) {
            int orow = row0 + kg * 4 + j;
            if (orow < M) {
                float v = fmaxf(acc[nt][j] + bv, 0.f);
                C[(size_t)orow * 128 + col] = fp8enc1(v);
            }
        }
    }
}

// ---------------- fused layer-2 agg + per-graph pool (4 rows/wave, fp8, replicated, 3 types) ----------------
__global__ __launch_bounds__(256) void aggpool3_kernel(
    const unsigned char* __restrict__ x0, const int* __restrict__ rpa, const int* __restrict__ csa,
    const int* __restrict__ ba, int Ma, float* __restrict__ pa,
    const unsigned char* __restrict__ x1, const int* __restrict__ rpb, const int* __restrict__ csb,
    const int* __restrict__ bb, int Mb, float* __restrict__ pb,
    const unsigned char* __restrict__ x2, const int* __restrict__ rpc, const int* __restrict__ csc,
    const int* __restrict__ bc, int Mc, float* __restrict__ pc)
{
    const unsigned char* xf8; const int *rp, *csr, *batch; int M; float* pool;
    if (blockIdx.y == 0) { xf8 = x0; rp = rpa; csr = csa; batch = ba; M = Ma; pool = pa; }
    else if (blockIdx.y == 1) { xf8 = x1; rp = rpb; csr = csb; batch = bb; M = Mb; pool = pb; }
    else { xf8 = x2; rp = rpc; csr = csc; batch = bc; M = Mc; pool = pc; }
    int wave = threadIdx.x >> 6, lane = threadIdx.x & 63;
    int r0 = (blockIdx.x * 4 + wave) * 4;
    if (r0 >= M) return;
    int r1 = min(M, r0 + 4);
    float* p = pool + (size_t)(blockIdx.x & (REP - 1)) * NG * 128;
    float ax = 0.f, ay = 0.f;
    int curg = batch[r0];
    for (int row = r0; row < r1; ++row) {
        int g = batch[row];
        if (g != curg) {
            atomicAdd(&p[curg * 128 + lane * 2],     ax);
            atomicAdd(&p[curg * 128 + lane * 2 + 1], ay);
            ax = 0.f; ay = 0.f; curg = g;
        }
        int s0 = rp[row], s1 = rp[row + 1];
        float sx = 0.f, sy = 0.f;
        int j = s0;
        for (; j + 8 <= s1; j += 8) GATHER8(j)
        for (; j < s1; ++j) {
            ushort w = *(const ushort*)&xf8[(size_t)csr[j] * 128 + lane * 2];
            f32x2 pv = fp8pair(w);
            sx += pv[0]; sy += pv[1];
        }
        int deg = s1 - s0;
        float sc = 1.f / (float)(deg > 1 ? deg : 1);
        ax += sx * sc; ay += sy * sc;
    }
    atomicAdd(&p[curg * 128 + lane * 2],     ax);
    atomicAdd(&p[curg * 128 + lane * 2 + 1], ay);
}

// ---------------- 2-way per-graph row-sum pool over fp8 rows (batch sorted) ----------------
__global__ __launch_bounds__(256) void pool2_kernel(
    const unsigned char* __restrict__ u1f, const unsigned char* __restrict__ d1f,
    const int* __restrict__ bndu, const int* __restrict__ bndd,
    float* __restrict__ pu1, float* __restrict__ pd1)
{
    const unsigned char* xf8; const int* bnd; float* pool;
    if (blockIdx.y == 0) { xf8 = u1f; bnd = bndu; pool = pu1; }
    else { xf8 = d1f; bnd = bndd; pool = pd1; }
    int g = blockIdx.x;
    int lo = bnd[g], hi = bnd[g + 1];
    int c2 = threadIdx.x & 63, half = threadIdx.x >> 6;
    float sx = 0.f, sy = 0.f;
    for (int r = lo + half; r < hi; r += 4) {
        ushort w = *(const ushort*)&xf8[(size_t)r * 128 + c2 * 2];
        f32x2 p = fp8pair(w);
        sx += p[0]; sy += p[1];
    }
    __shared__ float ls[256 * 2];
    ls[threadIdx.x * 2]     = sx;
    ls[threadIdx.x * 2 + 1] = sy;
    __syncthreads();
    if (half == 0) {
        float ox = ls[c2 * 2] + ls[(64 + c2) * 2] + ls[(128 + c2) * 2] + ls[(192 + c2) * 2];
        float oy = ls[c2 * 2 + 1] + ls[(64 + c2) * 2 + 1] + ls[(128 + c2) * 2 + 1] + ls[(192 + c2) * 2 + 1];
        pool[g * 128 + c2 * 2]     = ox;
        pool[g * 128 + c2 * 2 + 1] = oy;
    }
}

// ---------------- final: layer-2 matmuls at graph level + MLP + log_softmax ----------------
__global__ __launch_bounds__(128) void final_kernel(
    const float* __restrict__ pmdu, const float* __restrict__ pmuu, const float* __restrict__ pmud,
    const float* __restrict__ pu1,  const float* __restrict__ pd1,
    const int* __restrict__ bndu, const int* __restrict__ bndd,
    const float* __restrict__ Wl2_du, const float* __restrict__ bl2_du, const float* __restrict__ Wr2_du,
    const float* __restrict__ Wl2_uu, const float* __restrict__ bl2_uu, const float* __restrict__ Wr2_uu,
    const float* __restrict__ Wl2_ud, const float* __restrict__ bl2_ud, const float* __restrict__ Wr2_ud,
    const float* __restrict__ W1, const float* __restrict__ b1,
    const float* __restrict__ W2, const float* __restrict__ b2,
    float* __restrict__ out)
{
    int g = blockIdx.x, t = threadIdx.x;
    __shared__ float smdu[128], smuu[128], smud[128], su1[128], sd1[128];
    __shared__ float xrow[256], h[128], lg[2];
    float vdu = 0.f, vuu = 0.f, vud = 0.f;
    #pragma unroll
    for (int r = 0; r < REP; ++r) {
        vdu += pmdu[(size_t)r * NG * 128 + g * 128 + t];
        vuu += pmuu[(size_t)r * NG * 128 + g * 128 + t];
        vud += pmud[(size_t)r * NG * 128 + g * 128 + t];
    }
    smdu[t] = vdu;
    smuu[t] = vuu;
    smud[t] = vud;
    su1[t]  = pu1[g * 128 + t];
    sd1[t]  = pd1[g * 128 + t];
    __syncthreads();
    float ncu = (float)(bndu[g + 1] - bndu[g]);
    float ncd = (float)(bndd[g + 1] - bndd[g]);
    float cu = ncu > 1.f ? ncu : 1.f, cd = ncd > 1.f ? ncd : 1.f;
    float accu = ncu * (bl2_du[t] + bl2_uu[t]);
    float accd = ncd * bl2_ud[t];
    for (int k = 0; k < 128; ++k) {
        accu += smdu[k] * Wl2_du[k * 128 + t]
              + smuu[k] * Wl2_uu[k * 128 + t]
              + su1[k]  * (Wr2_du[k * 128 + t] + Wr2_uu[k * 128 + t]);
        accd += smud[k] * Wl2_ud[k * 128 + t]
              + sd1[k]  * Wr2_ud[k * 128 + t];
    }
    xrow[t]       = accu / cu;
    xrow[128 + t] = accd / cd;
    __syncthreads();
    float hh = b1[t];
    for (int k = 0; k < 256; ++k) hh += xrow[k] * W1[k * 128 + t];
    h[t] = fmaxf(hh, 0.f);
    __syncthreads();
    if (t < 2) {
        float l = b2[t];
        for (int k = 0; k < 128; ++k) l += h[k] * W2[k * 2 + t];
        lg[t] = l;
    }
    __syncthreads();
    if (t == 0) {
        float m = fmaxf(lg[0], lg[1]);
        float lse = m + logf(expf(lg[0] - m) + expf(lg[1] - m));
        out[g * 2 + 0] = lg[0] - lse;
        out[g * 2 + 1] = lg[1] - lse;
    }
}

extern "C" void kernel_launch(void* const* d_in, const int* in_sizes, int n_in,
                              void* d_out, int out_size, void* d_ws, size_t ws_size,
                              hipStream_t stream)
{
    const float* x_user = (const float*)d_in[0];
    const float* x_drug = (const float*)d_in[1];
    const int* ei_ud = (const int*)d_in[2];
    const int* ei_du = (const int*)d_in[3];
    const int* ei_uu = (const int*)d_in[4];
    const int* batch_u = (const int*)d_in[5];
    const int* batch_d = (const int*)d_in[6];
    const float* Wl1_ud = (const float*)d_in[7];  const float* bl1_ud = (const float*)d_in[8];  const float* Wr1_ud = (const float*)d_in[9];
    const float* Wl1_du = (const float*)d_in[10]; const float* bl1_du = (const float*)d_in[11]; const float* Wr1_du = (const float*)d_in[12];
    const float* Wl1_uu = (const float*)d_in[13]; const float* bl1_uu = (const float*)d_in[14]; const float* Wr1_uu = (const float*)d_in[15];
    const float* Wl2_ud = (const float*)d_in[16]; const float* bl2_ud = (const float*)d_in[17]; const float* Wr2_ud = (const float*)d_in[18];
    const float* Wl2_du = (const float*)d_in[19]; const float* bl2_du = (const float*)d_in[20]; const float* Wr2_du = (const float*)d_in[21];
    const float* Wl2_uu = (const float*)d_in[22]; const float* bl2_uu = (const float*)d_in[23]; const float* Wr2_uu = (const float*)d_in[24];
    const float* W1 = (const float*)d_in[25]; const float* b1 = (const float*)d_in[26];
    const float* W2 = (const float*)d_in[27]; const float* b2 = (const float*)d_in[28];
    (void)n_in; (void)out_size; (void)ws_size;

    const int Nu = in_sizes[0] / 128;
    const int Nd = in_sizes[1] / 128;
    const int E_ud = in_sizes[2] / 2;
    const int E_du = in_sizes[3] / 2;
    const int E_uu = in_sizes[4] / 2;
    const int nbk_u = (Nu + 63) >> 6;
    const int nbk_d = (Nd + 63) >> 6;
    const int nbk_max = nbk_u > nbk_d ? nbk_u : nbk_d;
    const int Nmax = Nu > Nd ? Nu : Nd;

    char* ws = (char*)d_ws;
    size_t off = 0;
    auto alloc = [&](size_t bytes) -> void* {
        void* p = ws + off;
        off = (off + bytes + 255) & ~(size_t)255;
        return p;
    };
    int2* ebuf_ud = (int2*)alloc((size_t)E_ud * 8);
    int2* ebuf_du = (int2*)alloc((size_t)E_du * 8);
    int2* ebuf_uu = (int2*)alloc((size_t)E_uu * 8);
    int* cntA_ud = (int*)alloc((size_t)NBK_MAX * GSC * 4);
    int* cntA_du = (int*)alloc((size_t)NBK_MAX * GSC * 4);
    int* cntA_uu = (int*)alloc((size_t)NBK_MAX * GSC * 4);
    int* btot_ud = (int*)alloc((size_t)NBK_MAX * 4);
    int* btot_du = (int*)alloc((size_t)NBK_MAX * 4);
    int* btot_uu = (int*)alloc((size_t)NBK_MAX * 4);
    int* bbase_ud = (int*)alloc((size_t)(NBK_MAX + 1) * 4);
    int* bbase_du = (int*)alloc((size_t)(NBK_MAX + 1) * 4);
    int* bbase_uu = (int*)alloc((size_t)(NBK_MAX + 1) * 4);
    int* csr_ud = (int*)alloc((size_t)(E_ud + 8) * 4);
    int* csr_du = (int*)alloc((size_t)(E_du + 8) * 4);
    int* csr_uu = (int*)alloc((size_t)(E_uu + 8) * 4);
    int* rp_ud = (int*)alloc((size_t)(Nd + 1) * 4);
    int* rp_du = (int*)alloc((size_t)(Nu + 1) * 4);
    int* rp_uu = (int*)alloc((size_t)(Nu + 1) * 4);
    ushort* xb_u = (ushort*)alloc((size_t)Nu * 128 * 2);    // bf16 (MFMA A-operand)
    ushort* xb_d = (ushort*)alloc((size_t)Nd * 128 * 2);
    unsigned char* xf8_u = (unsigned char*)alloc((size_t)Nu * 128);   // fp8 gather tables
    unsigned char* xf8_d = (unsigned char*)alloc((size_t)Nd * 128);
    // layer-1 mean buffers overlay the ebufs (dead after csrify)
    ushort* mean_du = (ushort*)ebuf_du;   // [Nu,128] bf16
    ushort* mean_uu = (ushort*)ebuf_uu;   // [Nu,128]
    ushort* mean_ud = (ushort*)ebuf_ud;   // [Nd,128]
    unsigned char* u1f = (unsigned char*)alloc((size_t)Nu * 128);   // layer-1 out, fp8
    unsigned char* d1f = (unsigned char*)alloc((size_t)Nd * 128);
    float* pmdu = (float*)alloc((size_t)REP * NG * 128 * 4);
    float* pmuu = (float*)alloc((size_t)REP * NG * 128 * 4);
    float* pmud = (float*)alloc((size_t)REP * NG * 128 * 4);
    char* zero2_beg = (char*)pmdu;
    char* zero2_end = ws + off;
    float* pu1  = (float*)alloc(NG * 128 * 4);
    float* pd1  = (float*)alloc(NG * 128 * 4);
    int* bnd_u = (int*)alloc((NG + 1) * 4);
    int* bnd_d = (int*)alloc((NG + 1) * 4);
    ushort* Wt_ru  = (ushort*)alloc(128 * 128 * 2);
    ushort* Wt_ldu = (ushort*)alloc(128 * 128 * 2);
    ushort* Wt_luu = (ushort*)alloc(128 * 128 * 2);
    ushort* Wt_rud = (ushort*)alloc(128 * 128 * 2);
    ushort* Wt_lud = (ushort*)alloc(128 * 128 * 2);
    float* b1s_u  = (float*)alloc(128 * 4);

    const int* dst_ud = ei_ud + E_ud;
    const int* dst_du = ei_du + E_du;
    const int* dst_uu = ei_uu + E_uu;

    // ---- CSR build via LDS bucket sort (zero device atomics), 3 types per launch ----
    bucket_count3<<<dim3(GSC, 3), 256, 0, stream>>>(
        dst_ud, E_ud, nbk_d, cntA_ud,
        dst_du, E_du, nbk_u, cntA_du,
        dst_uu, E_uu, nbk_u, cntA_uu);
    scan_blocks3<<<dim3(nbk_max, 3), GSC, 0, stream>>>(
        cntA_ud, nbk_d, btot_ud,
        cntA_du, nbk_u, btot_du,
        cntA_uu, nbk_u, btot_uu);
    scan_buckets3<<<3, 1024, 0, stream>>>(
        btot_ud, nbk_d, bbase_ud,
        btot_du, nbk_u, bbase_du,
        btot_uu, nbk_u, bbase_uu);
    bucket_scatter3<<<dim3(GSC, 3), 256, 0, stream>>>(
        ei_ud, dst_ud, E_ud, nbk_d, cntA_ud, bbase_ud, ebuf_ud,
        ei_du, dst_du, E_du, nbk_u, cntA_du, bbase_du, ebuf_du,
        ei_uu, dst_uu, E_uu, nbk_u, cntA_uu, bbase_uu, ebuf_uu);
    csrify3<<<dim3(nbk_max, 3), 256, 0, stream>>>(
        ebuf_ud, bbase_ud, Nd, E_ud, nbk_d, rp_ud, csr_ud,
        ebuf_du, bbase_du, Nu, E_du, nbk_u, rp_du, csr_du,
        ebuf_uu, bbase_uu, Nu, E_uu, nbk_u, rp_uu, csr_uu);

    // ---- prep (wprep+bias+bounds), conversions, pm memset ----
    prep_kernel<<<7, 256, 0, stream>>>(Wr1_du, Wr1_uu, Wt_ru,
                                       Wl1_du, Wt_ldu, Wl1_uu, Wt_luu,
                                       Wr1_ud, Wt_rud, Wl1_ud, Wt_lud,
                                       bl1_du, bl1_uu, b1s_u,
                                       batch_u, Nu, batch_d, Nd, bnd_u, bnd_d);
    cvt_dual2_kernel<<<dim3((Nmax * 32 + 255) / 256, 2), 256, 0, stream>>>(
        x_user, xb_u, xf8_u, Nu * 32,
        x_drug, xb_d, xf8_d, Nd * 32);
    hipMemsetAsync(zero2_beg, 0, (size_t)(zero2_end - zero2_beg), stream);

    // ---- layer-1 aggregation (fp8 gather, 3 types, one launch; means overlay dead ebufs) ----
    agg3_kernel<<<dim3((Nmax + 3) / 4, 3), 256, 0, stream>>>(
        xf8_d, rp_du, csr_du, Nu, mean_du,
        xf8_u, rp_uu, csr_uu, Nu, mean_uu,
        xf8_u, rp_ud, csr_ud, Nd, mean_ud);

    // ---- layer-1 MFMA GEMMs -> fp8 ----
    gemm_mfma<3><<<(Nu + 63) / 64, 256, 0, stream>>>(xb_u, mean_du, mean_uu,
                                                     Wt_ru, Wt_ldu, Wt_luu, Nu, b1s_u, u1f);
    gemm_mfma<2><<<(Nd + 63) / 64, 256, 0, stream>>>(xb_d, mean_ud, nullptr,
                                                     Wt_rud, Wt_lud, nullptr, Nd, bl1_ud, d1f);

    // ---- layer 2: fused CSR-mean + per-graph pool (fp8 gather, replicated, one launch) ----
    aggpool3_kernel<<<dim3((Nmax + 15) / 16, 3), 256, 0, stream>>>(
        d1f, rp_du, csr_du, batch_u, Nu, pmdu,
        u1f, rp_uu, csr_uu, batch_u, Nu, pmuu,
        u1f, rp_ud, csr_ud, batch_d, Nd, pmud);

    // ---- root-term pools (direct store, fp8 stream) ----
    pool2_kernel<<<dim3(NG, 2), 256, 0, stream>>>(u1f, d1f, bnd_u, bnd_d, pu1, pd1);

    // ---- graph-level layer-2 matmuls + MLP + log_softmax ----
    final_kernel<<<NG, 128, 0, stream>>>(pmdu, pmuu, pmud, pu1, pd1, bnd_u, bnd_d,
                                         Wl2_du, bl2_du, Wr2_du,
                                         Wl2_uu, bl2_uu, Wr2_uu,
                                         Wl2_ud, bl2_ud, Wr2_ud,
                                         W1, b1, W2, b2, (float*)d_out);
}